// Round 9
// baseline (272.188 us; speedup 1.0000x reference)
//
#include <hip/hip_runtime.h>
#include <hip/hip_bf16.h>
#include <math.h>

#define L_SZ 1024
#define DM   512
#define DI   1024
#define NS   16
#define CH   256

typedef float4 f4;
typedef __attribute__((ext_vector_type(8))) short short8;
typedef __attribute__((ext_vector_type(8))) unsigned short u16x8;
typedef __attribute__((ext_vector_type(4))) float f32x4;

__device__ __forceinline__ float bf2f(ushort u) {
    union { unsigned int i; float f; } x; x.i = ((unsigned int)u) << 16; return x.f;
}
__device__ __forceinline__ ushort f2bf(float f) {
    union { float f; unsigned int i; } x; x.f = f;
    unsigned int r = x.i + 0x7FFFu + ((x.i >> 16) & 1u);
    return (ushort)(r >> 16);
}
// packed RNE f32x2 -> bf16x2 (v_cvt_pk_bf16_f32 on gfx950)
__device__ __forceinline__ uint pkbf(float a, float b) {
    union { __hip_bfloat162 h; uint u; } c;
    c.h = __float22bfloat162_rn(make_float2(a, b));
    return c.u;
}

#define GLOAD16(gp, lp) \
  __builtin_amdgcn_global_load_lds((const __attribute__((address_space(1))) void*)(gp), \
                                   (__attribute__((address_space(3))) void*)(lp), 16, 0, 0)

// ------------------------------------------------------------------
// k_prep: ONE dispatch for all setup work. (unchanged)
// ------------------------------------------------------------------
__global__ __launch_bounds__(256) void k_prep(
    const float* __restrict__ s0, const float* __restrict__ s1,
    const float* __restrict__ s2, const float* __restrict__ s3,
    const float* __restrict__ s4, const float* __restrict__ s5,
    ushort* __restrict__ d0, ushort* __restrict__ d1,
    ushort* __restrict__ d2, ushort* __restrict__ d3,
    ushort* __restrict__ d4, ushort* __restrict__ d5,
    const float* __restrict__ xv, const float* __restrict__ xi,
    ushort* __restrict__ xtv, ushort* __restrict__ xti,
    float* __restrict__ p, unsigned int* __restrict__ cnt)
{
    __shared__ float tile[32][36];
    const int bid = blockIdx.x;
    const int t = threadIdx.x;
    if (bid < 2304) {
        const float* s; ushort* d; int rel;
        if      (bid < 128)  { s = s0; d = d0; rel = bid; }
        else if (bid < 256)  { s = s1; d = d1; rel = bid - 128; }
        else if (bid < 1280) { s = s2; d = d2; rel = bid - 256; }
        else                 { s = s3; d = d3; rel = bid - 1280; }
        const int i = rel * 256 + t;
        f4 v = ((const f4*)s)[i];
        ushort4 o;
        o.x = f2bf(v.x); o.y = f2bf(v.y); o.z = f2bf(v.z); o.w = f2bf(v.w);
        ((ushort4*)d)[i] = o;
        return;
    }
    if (bid < 3328) {
        const int rel = (bid < 2816) ? bid - 2304 : bid - 2816;
        const float* wo = (bid < 2816) ? s4 : s5;
        ushort* wt      = (bid < 2816) ? d4 : d5;
        const int kt = rel & 31, dt = rel >> 5;
        const int d0_ = dt * 32, k0 = kt * 32;
        {
            int cc = t >> 3, ll4 = (t & 7) << 2;
            f4 v = *(const f4*)(wo + (size_t)(d0_ + cc) * 1024 + k0 + ll4);
            tile[cc][ll4 + 0] = v.x; tile[cc][ll4 + 1] = v.y;
            tile[cc][ll4 + 2] = v.z; tile[cc][ll4 + 3] = v.w;
        }
        __syncthreads();
        {
            int ll = t >> 3, cc4 = (t & 7) << 2;
            ushort4 o;
            o.x = f2bf(tile[cc4 + 0][ll]); o.y = f2bf(tile[cc4 + 1][ll]);
            o.z = f2bf(tile[cc4 + 2][ll]); o.w = f2bf(tile[cc4 + 3][ll]);
            *(ushort4*)(wt + (size_t)(k0 + ll) * 512 + d0_ + cc4) = o;
        }
        return;
    }
    if (bid < 5376) {
        const int rel = bid - 3328;
        const int l0 = (rel & 31) * 32, c0 = ((rel >> 5) & 7) * 32;
        const int z = rel >> 8;
        const int b = z & 3, st = z >> 2;
        const float* x = st ? xi : xv;
        ushort* xt = st ? xti : xtv;
        {
            int cc = t >> 3, ll4 = (t & 7) << 2;
            f4 v = *(const f4*)(x + ((size_t)(b * CH + c0 + cc)) * L_SZ + l0 + ll4);
            tile[cc][ll4 + 0] = v.x; tile[cc][ll4 + 1] = v.y;
            tile[cc][ll4 + 2] = v.z; tile[cc][ll4 + 3] = v.w;
        }
        __syncthreads();
        {
            int ll = t >> 3, cc4 = (t & 7) << 2;
            ushort4 o;
            o.x = f2bf(tile[cc4 + 0][ll]); o.y = f2bf(tile[cc4 + 1][ll]);
            o.z = f2bf(tile[cc4 + 2][ll]); o.w = f2bf(tile[cc4 + 3][ll]);
            *(ushort4*)(xt + ((size_t)(b * L_SZ + l0 + ll)) * CH + c0 + cc4) = o;
        }
        return;
    }
    const f4 z4 = {0.f, 0.f, 0.f, 0.f};
    ((f4*)p)[t]       = z4;
    ((f4*)p)[t + 256] = z4;
    ((f4*)p)[t + 512] = z4;
    ((f4*)p)[t + 768] = z4;
    if (t == 0) *cnt = 0u;
}

// ------------------------------------------------------------------
// unified bf16 MFMA GEMM, tiled BM x BN (4 waves 2x2).
// double-buffered LDS + raw s_barrier + counted vmcnt. (unchanged)
// ------------------------------------------------------------------
template<int MODE, int BM, int BN, int OS>
__global__ __launch_bounds__(256) void k_gemm(
    const ushort* __restrict__ A0, const ushort* __restrict__ A1,
    const ushort* __restrict__ B0, const ushort* __restrict__ B1,
    int K,
    float* __restrict__ o0, float* __restrict__ o1,
    ushort* __restrict__ ob0, ushort* __restrict__ ob1,
    ushort* __restrict__ sb0, ushort* __restrict__ sb1,
    const float* __restrict__ pg, const float* __restrict__ pb,
    const float* __restrict__ pm, const float* __restrict__ pv,
    const float* __restrict__ x0, const float* __restrict__ x1,
    const float* __restrict__ gate, float* __restrict__ pp)
{
    constexpr int MT   = BM / 32;
    constexpr int NT   = BN / 32;
    constexpr int ASEG = BM / 16;
    constexpr int NSEG = (BM + BN) / 16;
    constexpr int SPW  = NSEG / 4;
    __shared__ __align__(16) ushort Sl[2][(BM + BN) * 32];
    const int t = threadIdx.x;
    const int wv = t >> 6, lane = t & 63;
    const int n0 = blockIdx.x * BN, m0 = blockIdx.y * BM;
    const int st = blockIdx.z;
    const ushort* Ap = st ? A1 : A0;
    const ushort* Bp = st ? B1 : B0;
    const int wm = wv >> 1, wn = wv & 1;
    const int lrow = lane & 15, q = lane >> 4;
    f32x4 acc[MT][NT];
    #pragma unroll
    for (int a_ = 0; a_ < MT; ++a_)
        #pragma unroll
        for (int b_ = 0; b_ < NT; ++b_)
            acc[a_][b_] = (f32x4){0.f, 0.f, 0.f, 0.f};
    const int srow = lane >> 2;
    const int skk  = (((lane & 3) ^ ((lane >> 3) & 3)) << 3);
    const int koff = ((q ^ ((lrow >> 1) & 3)) << 3);
    #pragma unroll
    for (int s2 = 0; s2 < SPW; ++s2) {
        const int seg = wv * SPW + s2;
        const int grow = (seg < ASEG) ? (m0 + seg * 16 + srow)
                                      : (n0 + (seg - ASEG) * 16 + srow);
        const ushort* src = (seg < ASEG) ? Ap : Bp;
        GLOAD16(src + (size_t)grow * K + skk, &Sl[0][seg * 512]);
    }
    int cur = 0;
    for (int k0 = 0; k0 < K; k0 += 32) {
        if (k0 + 32 < K) {
            #pragma unroll
            for (int s2 = 0; s2 < SPW; ++s2) {
                const int seg = wv * SPW + s2;
                const int grow = (seg < ASEG) ? (m0 + seg * 16 + srow)
                                              : (n0 + (seg - ASEG) * 16 + srow);
                const ushort* src = (seg < ASEG) ? Ap : Bp;
                GLOAD16(src + (size_t)grow * K + (k0 + 32) + skk, &Sl[cur ^ 1][seg * 512]);
            }
            if constexpr (SPW == 2)      asm volatile("s_waitcnt vmcnt(2)" ::: "memory");
            else if constexpr (SPW == 3) asm volatile("s_waitcnt vmcnt(3)" ::: "memory");
            else                         asm volatile("s_waitcnt vmcnt(4)" ::: "memory");
        } else {
            asm volatile("s_waitcnt vmcnt(0)" ::: "memory");
        }
        __builtin_amdgcn_s_barrier();
        short8 af[MT], bfr[NT];
        #pragma unroll
        for (int mt = 0; mt < MT; ++mt)
            af[mt] = *(const short8*)&Sl[cur][(wm * (MT * 16) + mt * 16 + lrow) * 32 + koff];
        #pragma unroll
        for (int nt = 0; nt < NT; ++nt)
            bfr[nt] = *(const short8*)&Sl[cur][(BM + wn * (NT * 16) + nt * 16 + lrow) * 32 + koff];
        #pragma unroll
        for (int mt = 0; mt < MT; ++mt)
            #pragma unroll
            for (int nt = 0; nt < NT; ++nt) {
                if constexpr (MODE == 1)
                    acc[mt][nt] = __builtin_amdgcn_mfma_f32_16x16x32_bf16(bfr[nt], af[mt], acc[mt][nt], 0, 0, 0);
                else
                    acc[mt][nt] = __builtin_amdgcn_mfma_f32_16x16x32_bf16(af[mt], bfr[nt], acc[mt][nt], 0, 0, 0);
            }
        asm volatile("s_waitcnt lgkmcnt(0)" ::: "memory");
        __builtin_amdgcn_sched_barrier(0);
        __builtin_amdgcn_s_barrier();
        cur ^= 1;
    }
    // epilogue; D layout: row = q*4 + r, col = lrow [m89-verified]
    if (MODE == 0) {
        ushort* sq = st ? ob1 : ob0;
        const int b = m0 >> 10;
        #pragma unroll
        for (int nt = 0; nt < NT; ++nt) {
            const int gn = n0 + wn * (NT * 16) + nt * 16 + lrow;
            const float s  = pg[gn] * rsqrtf(pv[gn] + 1e-5f);
            const float sh = pb[gn] - pm[gn] * s;
            float psum = 0.f;
            #pragma unroll
            for (int mt = 0; mt < MT; ++mt) {
                const int gm = m0 + wm * (MT * 16) + mt * 16 + q * 4;
                float v[4];
                #pragma unroll
                for (int r = 0; r < 4; ++r) {
                    v[r] = fmaxf(fmaf(acc[mt][nt][r], s, sh), 0.f);
                    psum += v[r];
                }
                const uint u01 = pkbf(v[0], v[1]);
                const uint u23 = pkbf(v[2], v[3]);
                ushort* bp = sq + (size_t)gm * DM + gn;
                bp[0]      = (ushort)u01;
                bp[DM]     = (ushort)(u01 >> 16);
                bp[2 * DM] = (ushort)u23;
                bp[3 * DM] = (ushort)(u23 >> 16);
            }
            psum += __shfl_xor(psum, 16, 64);
            psum += __shfl_xor(psum, 32, 64);
            if (q == 0)
                atomicAdd(pp + (b * 1024 + st * 512 + gn), psum * (1.0f / 1024.0f));
        }
    } else if (MODE == 1) {
        const bool isx = (n0 < 1024);
        ushort* xp = st ? ob1 : ob0;
        ushort* sp = st ? sb1 : sb0;
        #pragma unroll
        for (int mt = 0; mt < MT; ++mt) {
            const int gm = m0 + wm * (MT * 16) + mt * 16 + lrow;   // seq row
            #pragma unroll
            for (int nt = 0; nt < NT; ++nt) {
                const int gnb = n0 + wn * (NT * 16) + nt * 16 + q * 4;  // channel base
                if (isx) {
                    const uint u01 = pkbf(acc[mt][nt][0], acc[mt][nt][1]);
                    const uint u23 = pkbf(acc[mt][nt][2], acc[mt][nt][3]);
                    *(uint2*)(xp + (size_t)gm * DI + gnb) = make_uint2(u01, u23);
                } else {
                    float sv[4];
                    #pragma unroll
                    for (int r = 0; r < 4; ++r) {
                        const float v = acc[mt][nt][r];
                        sv[r] = v / (1.f + __expf(-v));
                    }
                    const uint u01 = pkbf(sv[0], sv[1]);
                    const uint u23 = pkbf(sv[2], sv[3]);
                    *(uint2*)(sp + (size_t)gm * DI + gnb - 1024) = make_uint2(u01, u23);
                }
            }
        }
    } else if (MODE == 2) {
        ushort* fp_ = st ? ob1 : ob0;
        #pragma unroll
        for (int nt = 0; nt < NT; ++nt) {
            const int gn = n0 + wn * (NT * 16) + nt * 16 + lrow;
            #pragma unroll
            for (int mt = 0; mt < MT; ++mt) {
                const int gm = m0 + wm * (MT * 16) + mt * 16 + q * 4;
                const uint u01 = pkbf(acc[mt][nt][0], acc[mt][nt][1]);
                const uint u23 = pkbf(acc[mt][nt][2], acc[mt][nt][3]);
                ushort* bp = fp_ + (size_t)gm * OS + gn;
                bp[0]      = (ushort)u01;
                bp[OS]     = (ushort)(u01 >> 16);
                bp[2 * OS] = (ushort)u23;
                bp[3 * OS] = (ushort)(u23 >> 16);
            }
        }
    } else {  // MODE 3
        const float* xin = st ? x1 : x0;
        float* op = st ? o1 : o0;
        const float g = 1.f / (1.f + __expf(-gate[0]));
        #pragma unroll
        for (int nt = 0; nt < NT; ++nt) {
            const int gn = n0 + wn * (NT * 16) + nt * 16 + lrow;   // channel c
            const float s  = pg[gn] * rsqrtf(pv[gn] + 1e-5f);
            const float sh = pb[gn] - pm[gn] * s;
            #pragma unroll
            for (int mt = 0; mt < MT; ++mt) {
                const int gmb = m0 + wm * (MT * 16) + mt * 16 + q * 4;
                const int b = gmb >> 10, l = gmb & 1023;
                const size_t off = ((size_t)(b * CH + gn)) * L_SZ + l;
                f4 xi = *(const f4*)(xin + off);
                f4 o;
                o.x = xi.x + g * fmaf(acc[mt][nt][0], s, sh);
                o.y = xi.y + g * fmaf(acc[mt][nt][1], s, sh);
                o.z = xi.z + g * fmaf(acc[mt][nt][2], s, sh);
                o.w = xi.w + g * fmaf(acc[mt][nt][3], s, sh);
                *(f4*)(op + off) = o;
            }
        }
    }
}

// ------------------------------------------------------------------
// fused LN + cast  AND  lam MLP (blocks >= 1024) in one dispatch.
// (unchanged from v15)
// ------------------------------------------------------------------
__global__ __launch_bounds__(256) void k_lnlam(
    const ushort* __restrict__ seq0, const ushort* __restrict__ seq1,
    const float* __restrict__ g0, const float* __restrict__ b0,
    const float* __restrict__ g1, const float* __restrict__ b1,
    ushort* __restrict__ ln0, ushort* __restrict__ ln1,
    const float* __restrict__ p, const float* __restrict__ w1,
    const float* __restrict__ lb1, const float* __restrict__ w2,
    const float* __restrict__ lb2, float* __restrict__ h1,
    float* __restrict__ lamo, unsigned int* __restrict__ cnt)
{
    const int t = threadIdx.x, lane = t & 63, wv = t >> 6;
    if (blockIdx.x >= 1024) {
        __shared__ float lsm[8];
        __shared__ unsigned int tick;
        const int lbk = (blockIdx.x - 1024) * 2 + blockIdx.y;   // 0..127
        const int idx = lbk * 4 + wv;    // 0..511
        const int b = idx >> 7, j = idx & 127;
        const float* pb = p + b * 1024;
        const float* wr = w1 + j * 1024;
        float s = 0.f;
        #pragma unroll
        for (int k = 0; k < 16; ++k)
            s = fmaf(pb[lane + k * 64], wr[lane + k * 64], s);
        #pragma unroll
        for (int off = 1; off < 64; off <<= 1) s += __shfl_xor(s, off, 64);
        if (lane == 0) h1[idx] = fmaxf(s + lb1[j], 0.f);
        __threadfence();
        __syncthreads();
        if (t == 0) tick = atomicAdd(cnt, 1u);
        __syncthreads();
        if (tick != 127u) return;
        __threadfence();
        {
            const int g32 = t >> 5, l32 = t & 31;
            const int bb = g32 >> 1, kk = g32 & 1;
            const float* hb = h1 + bb * 128;
            const float* wr2 = w2 + kk * 128;
            float ss = 0.f;
            #pragma unroll
            for (int u = 0; u < 4; ++u)
                ss = fmaf(hb[l32 + u * 32], wr2[l32 + u * 32], ss);
            #pragma unroll
            for (int off = 1; off < 32; off <<= 1) ss += __shfl_xor(ss, off, 64);
            if (l32 == 0) lsm[g32] = ss + lb2[kk];
        }
        __syncthreads();
        if (t < 4) {
            const float a0 = lsm[t * 2], a1 = lsm[t * 2 + 1];
            const float m  = fmaxf(a0, a1);
            const float e0 = __expf(a0 - m), e1 = __expf(a1 - m);
            const float inv = 1.f / (e0 + e1);
            lamo[t * 2 + 0] = e0 * inv;
            lamo[t * 2 + 1] = e1 * inv;
        }
        return;
    }
    const int row = blockIdx.x * 4 + wv, st = blockIdx.y;
    const ushort* seq = st ? seq1 : seq0;
    const float* gg  = st ? g1 : g0;
    const float* bb  = st ? b1 : b0;
    ushort* ln = st ? ln1 : ln0;
    const u16x8 v = *(const u16x8*)(seq + (size_t)row * DM + lane * 8);
    float f[8];
    float s = 0.f, ss = 0.f;
    #pragma unroll
    for (int i = 0; i < 8; ++i) {
        f[i] = bf2f(v[i]);
        s += f[i];
        ss = fmaf(f[i], f[i], ss);
    }
    #pragma unroll
    for (int off = 1; off < 64; off <<= 1) {
        s += __shfl_xor(s, off, 64); ss += __shfl_xor(ss, off, 64);
    }
    const float mu = s * (1.f / 512.f);
    const float rstd = rsqrtf(ss * (1.f / 512.f) - mu * mu + 1e-5f);
    const f4 gv0 = *(const f4*)(gg + lane * 8);
    const f4 gv1 = *(const f4*)(gg + lane * 8 + 4);
    const f4 bv0 = *(const f4*)(bb + lane * 8);
    const f4 bv1 = *(const f4*)(bb + lane * 8 + 4);
    const float gvv[8] = {gv0.x, gv0.y, gv0.z, gv0.w, gv1.x, gv1.y, gv1.z, gv1.w};
    const float bvv[8] = {bv0.x, bv0.y, bv0.z, bv0.w, bv1.x, bv1.y, bv1.z, bv1.w};
    u16x8 o;
    #pragma unroll
    for (int i = 0; i < 8; i += 2) {
        const uint u = pkbf(fmaf((f[i]     - mu) * rstd, gvv[i],     bvv[i]),
                            fmaf((f[i + 1] - mu) * rstd, gvv[i + 1], bvv[i + 1]));
        o[i]     = (ushort)u;
        o[i + 1] = (ushort)(u >> 16);
    }
    *(u16x8*)(ln + (size_t)row * DM + lane * 8) = o;
}

// ------------------------------------------------------------------
// SSM scan v16: direction-per-wave + state-split lanes.
//  - 256 threads: waves 0-1 = fwd, waves 2-3 = bwd; each thread owns
//    8 states (shalf) of one channel+direction -> serial chain and
//    per-wave program HALVE; waves/CU rises (48 KB LDS -> 3 blk/CU,
//    12 waves/CU vs v14's ~8).
//  - y = yh + shfl_xor(yh,1) reproduces v14's ye_+yo_ exactly.
//  - fwd/bwd exchange via 16 KB LDS stash (bf16, same f2bf rounding
//    as v14's packed words) + ONE mid-barrier.
//  - per lane-pair, lane (m&1) does the stash/sg/store for row m.
// ------------------------------------------------------------------
__global__ __launch_bounds__(256, 2) void k_scan(
    const ushort* __restrict__ xsV, const ushort* __restrict__ xsI,
    const ushort* __restrict__ sgV, const ushort* __restrict__ sgI,
    const float* __restrict__ VA, const float* __restrict__ VB,
    const float* __restrict__ VC, const float* __restrict__ IA,
    const float* __restrict__ IB, const float* __restrict__ IC,
    const float* __restrict__ lam,
    ushort* __restrict__ yV, ushort* __restrict__ yI)
{
    __shared__ __align__(16) ushort xt[256][64];   // 32 KB
    __shared__ ushort ys[2][64][64];               // 16 KB stash
    const int t = threadIdx.x;
    const int dir = t >> 7;                 // 0 = fwd (waves 0-1), 1 = bwd
    const int shalf = t & 1;                // which 8 states
    const int il = (t & 127) >> 1;          // 0..63 channel within block
    const int b = blockIdx.y;
    const int st = blockIdx.z >> 3, j = blockIdx.z & 7;
    const int c0 = blockIdx.x * 64;
    const ushort* xrow  = (st ? xsI : xsV) + (size_t)b * L_SZ * DI + c0;
    const ushort* sgrow = (st ? sgI : sgV) + (size_t)b * L_SZ * DI + c0;
    ushort* yrow        = (st ? yI  : yV ) + (size_t)b * L_SZ * DI + c0;
    const float* Alog = st ? IA : VA;
    const float* Cm   = st ? IC : VC;
    const float* Bown = st ? IB : VB;
    const float* Both = st ? VB : IB;
    const float lam0 = lam[b * 2 + 0], lam1 = lam[b * 2 + 1];
    const int row0 = j << 7;                // 128-row chunk
    // stage 256 rows x 64 ch; 256 threads x 8 x 16B. Dest includes srow
    // (wave-correct readfirstlane base, rule #21).
    const int srow = t >> 3;                // 0..31
    const int scol = (t & 7) << 3;
    #pragma unroll
    for (int i = 0; i < 8; ++i) {
        int r = row0 - 64 + i * 32 + srow;
        r = max(0, min(1023, r));
        GLOAD16(xrow + (size_t)r * DI + scol, &xt[i * 32 + srow][0]);
    }
    // per-lane params: 8 states of one direction
    float a[8], w[8], g[8];
    {
        const int cb = (c0 + il) * NS + shalf * 8;
        #pragma unroll
        for (int s4 = 0; s4 < 2; ++s4) {
            const f4 av = *(const f4*)(Alog + cb + s4 * 4);
            const f4 cv = *(const f4*)(Cm   + cb + s4 * 4);
            const f4 bo = *(const f4*)(Bown + cb + s4 * 4);
            const f4 bt = *(const f4*)(Both + cb + s4 * 4);
            const float avv[4] = {av.x, av.y, av.z, av.w};
            const float cvv[4] = {cv.x, cv.y, cv.z, cv.w};
            const float bov[4] = {bo.x, bo.y, bo.z, bo.w};
            const float btv[4] = {bt.x, bt.y, bt.z, bt.w};
            #pragma unroll
            for (int q = 0; q < 4; ++q) {
                const int s = s4 * 4 + q;
                a[s] = fminf(fmaxf(-__expf(avv[q]), -10.f), -0.01f);
                w[s] = 0.5f * cvv[q] * fmaf(lam0, bov[q], lam1 * btv[q]);
                g[s] = 0.f;
            }
        }
    }
    __syncthreads();

    const ushort* xtf = &xt[0][0];
    int toff = (dir ? 255 : 0) * 64 + il;
    const int tstep = dir ? -64 : 64;

    // warmup: 64 rows
    #pragma unroll 8
    for (int n = 0; n < 64; ++n) {
        const float v = bf2f(xtf[toff]); toff += tstep;
        #pragma unroll
        for (int s = 0; s < 8; ++s) g[s] = fmaf(a[s], g[s], v);
    }
    if ((j == 0 && dir == 0) || (j == 7 && dir == 1)) {
        #pragma unroll
        for (int s = 0; s < 8; ++s) g[s] = 0.f;
    }

    // phase A: this direction's first 64 output rows -> LDS stash
    #pragma unroll 8
    for (int m = 0; m < 64; ++m) {
        const float v = bf2f(xtf[toff]); toff += tstep;
        float yh = 0.f;
        #pragma unroll
        for (int s = 0; s < 8; ++s) {
            g[s] = fmaf(a[s], g[s], v);
            yh   = fmaf(g[s], w[s], yh);
        }
        const float y = yh + __shfl_xor(yh, 1, 64);
        if ((m & 1) == shalf) ys[dir][m][il] = f2bf(y);
    }
    __syncthreads();

    // phase B: last 64 rows; combine with opposite-direction stash, store.
    #pragma unroll 8
    for (int m = 64; m < 128; ++m) {
        const float v = bf2f(xtf[toff]); toff += tstep;
        float yh = 0.f;
        #pragma unroll
        for (int s = 0; s < 8; ++s) {
            g[s] = fmaf(a[s], g[s], v);
            yh   = fmaf(g[s], w[s], yh);
        }
        const float y = yh + __shfl_xor(yh, 1, 64);
        if ((m & 1) == shalf) {
            const int r = row0 + (dir ? 127 - m : m);
            const float z = (y + bf2f(ys[dir ^ 1][127 - m][il]))
                          * bf2f(sgrow[(size_t)r * DI + il]);
            yrow[(size_t)r * DI + il] = f2bf(z);
        }
    }
}

// ------------------------------------------------------------------
extern "C" void kernel_launch(void* const* d_in, const int* in_sizes, int n_in,
                              void* d_out, int out_size, void* d_ws, size_t ws_size,
                              hipStream_t stream)
{
    const float* xV       = (const float*)d_in[0];
    const float* xI       = (const float*)d_in[1];
    const float* convredw = (const float*)d_in[2];
    const float* bnredg   = (const float*)d_in[3];
    const float* bnredb   = (const float*)d_in[4];
    const float* bnredm   = (const float*)d_in[5];
    const float* bnredv   = (const float*)d_in[6];
    const float* convresw = (const float*)d_in[7];
    const float* bnresg   = (const float*)d_in[8];
    const float* bnresb   = (const float*)d_in[9];
    const float* bnresm   = (const float*)d_in[10];
    const float* bnresv   = (const float*)d_in[11];
    const float* lamw1    = (const float*)d_in[12];
    const float* lamb1    = (const float*)d_in[13];
    const float* lamw2    = (const float*)d_in[14];
    const float* lamb2    = (const float*)d_in[15];
    const float* Vinw     = (const float*)d_in[16];
    const float* Voutw    = (const float*)d_in[17];
    const float* VAlog    = (const float*)d_in[18];
    const float* VB       = (const float*)d_in[19];
    const float* VC       = (const float*)d_in[20];
    const float* Vlng     = (const float*)d_in[21];
    const float* Vlnb     = (const float*)d_in[22];
    const float* Iinw     = (const float*)d_in[23];
    const float* Ioutw    = (const float*)d_in[24];
    const float* IAlog    = (const float*)d_in[25];
    const float* IB       = (const float*)d_in[26];
    const float* IC       = (const float*)d_in[27];
    const float* Ilng     = (const float*)d_in[28];
    const float* Ilnb     = (const float*)d_in[29];
    const float* gate     = (const float*)d_in[30];

    char* W = (char*)d_ws;
    const size_t MB = 1048576;
    ushort* seqV  = (ushort*)(W + 0);            // 4 MB bf16 (4096,512)
    ushort* seqI  = (ushort*)(W + 4  * MB);      // 4 MB
    float*  p     = (float*)(W + 8 * MB);        // 16 KB
    float*  lam   = (float*)(W + 8 * MB + 16384);
    float*  h1    = (float*)(W + 8 * MB + 32768);
    unsigned int* cnt = (unsigned int*)(W + 8 * MB + 49152);
    ushort* sgV   = (ushort*)(W + 17 * MB);      // 8 MB bf16 (4096,1024)
    ushort* sgI   = (ushort*)(W + 25 * MB);
    ushort* yV    = (ushort*)(W + 33 * MB);      // 8 MB bf16 (4096,1024)
    ushort* yI    = (ushort*)(W + 41 * MB);
    ushort* wred  = (ushort*)(W + 65 * MB);      // 256 KB
    ushort* wres  = (ushort*)(W + 65 * MB + 262144);
    ushort* winV  = (ushort*)(W + 66 * MB);      // 2 MB
    ushort* winI  = (ushort*)(W + 68 * MB);
    ushort* woTv  = (ushort*)(W + 70 * MB);      // 1 MB bf16 (1024,512) = Voutw^T
    ushort* woTi  = (ushort*)(W + 71 * MB);
    ushort* xtV   = (ushort*)(W + 72 * MB);      // 2 MB
    ushort* xtI   = (ushort*)(W + 74 * MB);
    ushort* lnV   = (ushort*)(W + 76 * MB);      // 4 MB
    ushort* lnI   = (ushort*)(W + 80 * MB);
    ushort* xsV   = (ushort*)(W + 84 * MB);      // 8 MB bf16 (4096,1024)
    ushort* xsI   = (ushort*)(W + 92 * MB);
    ushort* wcombV = (ushort*)(W + 100 * MB);    // 512 KB bf16 (256,1024)
    ushort* wcombI = (ushort*)(W + 100 * MB + 524288);   // top = 101 MB
    float*  outp  = (float*)d_out;

    // prep: weight casts + wout transposes + x transpose + zero p/cnt
    k_prep<<<dim3(5377), 256, 0, stream>>>(
        convredw, convresw, Vinw, Iinw, Voutw, Ioutw,
        wred, wres, winV, winI, woTv, woTi,
        xV, xI, xtV, xtI, p, cnt);
    // wcomb[c,k] = sum_d wres[c,d]*wout[d,k]  (256x1024, K=512, bf16 out)
    k_gemm<2, 64, 64, 1024><<<dim3(16, 4, 2), 256, 0, stream>>>(
        wres, wres, woTv, woTi, 512,
        nullptr, nullptr, wcombV, wcombI, nullptr, nullptr,
        nullptr, nullptr, nullptr, nullptr, nullptr, nullptr, nullptr, nullptr);
    // conv_red (MFMA, 128x64) -> seq bf16 + fused pool
    k_gemm<0, 128, 64, 512><<<dim3(8, 32, 2), 256, 0, stream>>>(xtV, xtI, wred, wred, 256,
        nullptr, nullptr, seqV, seqI, nullptr, nullptr,
        bnredg, bnredb, bnredm, bnredv, nullptr, nullptr, nullptr, p);
    // LN -> bf16  +  lambda MLP (fused, one dispatch)
    k_lnlam<<<dim3(1088, 2), 256, 0, stream>>>(
        seqV, seqI, Vlng, Vlnb, Ilng, Ilnb, lnV, lnI,
        p, lamw1, lamb1, lamw2, lamb2, h1, lam, cnt);
    // in_proj (MFMA, 128x128) -> xs bf16, sg bf16
    k_gemm<1, 128, 128, 512><<<dim3(16, 32, 2), 256, 0, stream>>>(lnV, lnI, winV, winI, 512,
        nullptr, nullptr, xsV, xsI, sgV, sgI,
        nullptr, nullptr, nullptr, nullptr, nullptr, nullptr, nullptr, nullptr);
    // fused bidirectional scan v16 -> y bf16 (128-row chunks, 256 thr)
    k_scan<<<dim3(16, 4, 16), 256, 0, stream>>>(xsV, xsI, sgV, sgI,
        VAlog, VB, VC, IAlog, IB, IC, lam, yV, yI);
    // fused out-proj+conv_res (MFMA, 64x64, K=1024, B=wcomb) + residual -> d_out
    k_gemm<3, 64, 64, 512><<<dim3(4, 64, 2), 256, 0, stream>>>(yV, yI, wcombV, wcombI, 1024,
        outp, outp + 1048576, nullptr, nullptr, nullptr, nullptr,
        bnresg, bnresb, bnresm, bnresv, xV, xI, gate, nullptr);
}

// Round 10
// 233.395 us; speedup vs baseline: 1.1662x; 1.1662x over previous
//
#include <hip/hip_runtime.h>
#include <hip/hip_bf16.h>
#include <math.h>

#define L_SZ 1024
#define DM   512
#define DI   1024
#define NS   16
#define CH   256

typedef float4 f4;
typedef __attribute__((ext_vector_type(8))) short short8;
typedef __attribute__((ext_vector_type(8))) unsigned short u16x8;
typedef __attribute__((ext_vector_type(4))) float f32x4;

__device__ __forceinline__ float bf2f(ushort u) {
    union { unsigned int i; float f; } x; x.i = ((unsigned int)u) << 16; return x.f;
}
__device__ __forceinline__ ushort f2bf(float f) {
    union { float f; unsigned int i; } x; x.f = f;
    unsigned int r = x.i + 0x7FFFu + ((x.i >> 16) & 1u);
    return (ushort)(r >> 16);
}
// packed RNE f32x2 -> bf16x2 (v_cvt_pk_bf16_f32 on gfx950)
__device__ __forceinline__ uint pkbf(float a, float b) {
    union { __hip_bfloat162 h; uint u; } c;
    c.h = __float22bfloat162_rn(make_float2(a, b));
    return c.u;
}

#define GLOAD16(gp, lp) \
  __builtin_amdgcn_global_load_lds((const __attribute__((address_space(1))) void*)(gp), \
                                   (__attribute__((address_space(3))) void*)(lp), 16, 0, 0)

// ------------------------------------------------------------------
// k_prep: ONE dispatch for all setup work. (unchanged)
// ------------------------------------------------------------------
__global__ __launch_bounds__(256) void k_prep(
    const float* __restrict__ s0, const float* __restrict__ s1,
    const float* __restrict__ s2, const float* __restrict__ s3,
    const float* __restrict__ s4, const float* __restrict__ s5,
    ushort* __restrict__ d0, ushort* __restrict__ d1,
    ushort* __restrict__ d2, ushort* __restrict__ d3,
    ushort* __restrict__ d4, ushort* __restrict__ d5,
    const float* __restrict__ xv, const float* __restrict__ xi,
    ushort* __restrict__ xtv, ushort* __restrict__ xti,
    float* __restrict__ p, unsigned int* __restrict__ cnt)
{
    __shared__ float tile[32][36];
    const int bid = blockIdx.x;
    const int t = threadIdx.x;
    if (bid < 2304) {
        const float* s; ushort* d; int rel;
        if      (bid < 128)  { s = s0; d = d0; rel = bid; }
        else if (bid < 256)  { s = s1; d = d1; rel = bid - 128; }
        else if (bid < 1280) { s = s2; d = d2; rel = bid - 256; }
        else                 { s = s3; d = d3; rel = bid - 1280; }
        const int i = rel * 256 + t;
        f4 v = ((const f4*)s)[i];
        ushort4 o;
        o.x = f2bf(v.x); o.y = f2bf(v.y); o.z = f2bf(v.z); o.w = f2bf(v.w);
        ((ushort4*)d)[i] = o;
        return;
    }
    if (bid < 3328) {
        const int rel = (bid < 2816) ? bid - 2304 : bid - 2816;
        const float* wo = (bid < 2816) ? s4 : s5;
        ushort* wt      = (bid < 2816) ? d4 : d5;
        const int kt = rel & 31, dt = rel >> 5;
        const int d0_ = dt * 32, k0 = kt * 32;
        {
            int cc = t >> 3, ll4 = (t & 7) << 2;
            f4 v = *(const f4*)(wo + (size_t)(d0_ + cc) * 1024 + k0 + ll4);
            tile[cc][ll4 + 0] = v.x; tile[cc][ll4 + 1] = v.y;
            tile[cc][ll4 + 2] = v.z; tile[cc][ll4 + 3] = v.w;
        }
        __syncthreads();
        {
            int ll = t >> 3, cc4 = (t & 7) << 2;
            ushort4 o;
            o.x = f2bf(tile[cc4 + 0][ll]); o.y = f2bf(tile[cc4 + 1][ll]);
            o.z = f2bf(tile[cc4 + 2][ll]); o.w = f2bf(tile[cc4 + 3][ll]);
            *(ushort4*)(wt + (size_t)(k0 + ll) * 512 + d0_ + cc4) = o;
        }
        return;
    }
    if (bid < 5376) {
        const int rel = bid - 3328;
        const int l0 = (rel & 31) * 32, c0 = ((rel >> 5) & 7) * 32;
        const int z = rel >> 8;
        const int b = z & 3, st = z >> 2;
        const float* x = st ? xi : xv;
        ushort* xt = st ? xti : xtv;
        {
            int cc = t >> 3, ll4 = (t & 7) << 2;
            f4 v = *(const f4*)(x + ((size_t)(b * CH + c0 + cc)) * L_SZ + l0 + ll4);
            tile[cc][ll4 + 0] = v.x; tile[cc][ll4 + 1] = v.y;
            tile[cc][ll4 + 2] = v.z; tile[cc][ll4 + 3] = v.w;
        }
        __syncthreads();
        {
            int ll = t >> 3, cc4 = (t & 7) << 2;
            ushort4 o;
            o.x = f2bf(tile[cc4 + 0][ll]); o.y = f2bf(tile[cc4 + 1][ll]);
            o.z = f2bf(tile[cc4 + 2][ll]); o.w = f2bf(tile[cc4 + 3][ll]);
            *(ushort4*)(xt + ((size_t)(b * L_SZ + l0 + ll)) * CH + c0 + cc4) = o;
        }
        return;
    }
    const f4 z4 = {0.f, 0.f, 0.f, 0.f};
    ((f4*)p)[t]       = z4;
    ((f4*)p)[t + 256] = z4;
    ((f4*)p)[t + 512] = z4;
    ((f4*)p)[t + 768] = z4;
    if (t == 0) *cnt = 0u;
}

// ------------------------------------------------------------------
// unified bf16 MFMA GEMM, tiled BM x BN (4 waves 2x2).
// double-buffered LDS + raw s_barrier + counted vmcnt. (unchanged)
// ------------------------------------------------------------------
template<int MODE, int BM, int BN, int OS>
__global__ __launch_bounds__(256) void k_gemm(
    const ushort* __restrict__ A0, const ushort* __restrict__ A1,
    const ushort* __restrict__ B0, const ushort* __restrict__ B1,
    int K,
    float* __restrict__ o0, float* __restrict__ o1,
    ushort* __restrict__ ob0, ushort* __restrict__ ob1,
    ushort* __restrict__ sb0, ushort* __restrict__ sb1,
    const float* __restrict__ pg, const float* __restrict__ pb,
    const float* __restrict__ pm, const float* __restrict__ pv,
    const float* __restrict__ x0, const float* __restrict__ x1,
    const float* __restrict__ gate, float* __restrict__ pp)
{
    constexpr int MT   = BM / 32;
    constexpr int NT   = BN / 32;
    constexpr int ASEG = BM / 16;
    constexpr int NSEG = (BM + BN) / 16;
    constexpr int SPW  = NSEG / 4;
    __shared__ __align__(16) ushort Sl[2][(BM + BN) * 32];
    const int t = threadIdx.x;
    const int wv = t >> 6, lane = t & 63;
    const int n0 = blockIdx.x * BN, m0 = blockIdx.y * BM;
    const int st = blockIdx.z;
    const ushort* Ap = st ? A1 : A0;
    const ushort* Bp = st ? B1 : B0;
    const int wm = wv >> 1, wn = wv & 1;
    const int lrow = lane & 15, q = lane >> 4;
    f32x4 acc[MT][NT];
    #pragma unroll
    for (int a_ = 0; a_ < MT; ++a_)
        #pragma unroll
        for (int b_ = 0; b_ < NT; ++b_)
            acc[a_][b_] = (f32x4){0.f, 0.f, 0.f, 0.f};
    const int srow = lane >> 2;
    const int skk  = (((lane & 3) ^ ((lane >> 3) & 3)) << 3);
    const int koff = ((q ^ ((lrow >> 1) & 3)) << 3);
    #pragma unroll
    for (int s2 = 0; s2 < SPW; ++s2) {
        const int seg = wv * SPW + s2;
        const int grow = (seg < ASEG) ? (m0 + seg * 16 + srow)
                                      : (n0 + (seg - ASEG) * 16 + srow);
        const ushort* src = (seg < ASEG) ? Ap : Bp;
        GLOAD16(src + (size_t)grow * K + skk, &Sl[0][seg * 512]);
    }
    int cur = 0;
    for (int k0 = 0; k0 < K; k0 += 32) {
        if (k0 + 32 < K) {
            #pragma unroll
            for (int s2 = 0; s2 < SPW; ++s2) {
                const int seg = wv * SPW + s2;
                const int grow = (seg < ASEG) ? (m0 + seg * 16 + srow)
                                              : (n0 + (seg - ASEG) * 16 + srow);
                const ushort* src = (seg < ASEG) ? Ap : Bp;
                GLOAD16(src + (size_t)grow * K + (k0 + 32) + skk, &Sl[cur ^ 1][seg * 512]);
            }
            if constexpr (SPW == 2)      asm volatile("s_waitcnt vmcnt(2)" ::: "memory");
            else if constexpr (SPW == 3) asm volatile("s_waitcnt vmcnt(3)" ::: "memory");
            else                         asm volatile("s_waitcnt vmcnt(4)" ::: "memory");
        } else {
            asm volatile("s_waitcnt vmcnt(0)" ::: "memory");
        }
        __builtin_amdgcn_s_barrier();
        short8 af[MT], bfr[NT];
        #pragma unroll
        for (int mt = 0; mt < MT; ++mt)
            af[mt] = *(const short8*)&Sl[cur][(wm * (MT * 16) + mt * 16 + lrow) * 32 + koff];
        #pragma unroll
        for (int nt = 0; nt < NT; ++nt)
            bfr[nt] = *(const short8*)&Sl[cur][(BM + wn * (NT * 16) + nt * 16 + lrow) * 32 + koff];
        #pragma unroll
        for (int mt = 0; mt < MT; ++mt)
            #pragma unroll
            for (int nt = 0; nt < NT; ++nt) {
                if constexpr (MODE == 1)
                    acc[mt][nt] = __builtin_amdgcn_mfma_f32_16x16x32_bf16(bfr[nt], af[mt], acc[mt][nt], 0, 0, 0);
                else
                    acc[mt][nt] = __builtin_amdgcn_mfma_f32_16x16x32_bf16(af[mt], bfr[nt], acc[mt][nt], 0, 0, 0);
            }
        asm volatile("s_waitcnt lgkmcnt(0)" ::: "memory");
        __builtin_amdgcn_sched_barrier(0);
        __builtin_amdgcn_s_barrier();
        cur ^= 1;
    }
    // epilogue; D layout: row = q*4 + r, col = lrow [m89-verified]
    if (MODE == 0) {
        ushort* sq = st ? ob1 : ob0;
        const int b = m0 >> 10;
        #pragma unroll
        for (int nt = 0; nt < NT; ++nt) {
            const int gn = n0 + wn * (NT * 16) + nt * 16 + lrow;
            const float s  = pg[gn] * rsqrtf(pv[gn] + 1e-5f);
            const float sh = pb[gn] - pm[gn] * s;
            float psum = 0.f;
            #pragma unroll
            for (int mt = 0; mt < MT; ++mt) {
                const int gm = m0 + wm * (MT * 16) + mt * 16 + q * 4;
                float v[4];
                #pragma unroll
                for (int r = 0; r < 4; ++r) {
                    v[r] = fmaxf(fmaf(acc[mt][nt][r], s, sh), 0.f);
                    psum += v[r];
                }
                const uint u01 = pkbf(v[0], v[1]);
                const uint u23 = pkbf(v[2], v[3]);
                ushort* bp = sq + (size_t)gm * DM + gn;
                bp[0]      = (ushort)u01;
                bp[DM]     = (ushort)(u01 >> 16);
                bp[2 * DM] = (ushort)u23;
                bp[3 * DM] = (ushort)(u23 >> 16);
            }
            psum += __shfl_xor(psum, 16, 64);
            psum += __shfl_xor(psum, 32, 64);
            if (q == 0)
                atomicAdd(pp + (b * 1024 + st * 512 + gn), psum * (1.0f / 1024.0f));
        }
    } else if (MODE == 1) {
        const bool isx = (n0 < 1024);
        ushort* xp = st ? ob1 : ob0;
        ushort* sp = st ? sb1 : sb0;
        #pragma unroll
        for (int mt = 0; mt < MT; ++mt) {
            const int gm = m0 + wm * (MT * 16) + mt * 16 + lrow;   // seq row
            #pragma unroll
            for (int nt = 0; nt < NT; ++nt) {
                const int gnb = n0 + wn * (NT * 16) + nt * 16 + q * 4;  // channel base
                if (isx) {
                    const uint u01 = pkbf(acc[mt][nt][0], acc[mt][nt][1]);
                    const uint u23 = pkbf(acc[mt][nt][2], acc[mt][nt][3]);
                    *(uint2*)(xp + (size_t)gm * DI + gnb) = make_uint2(u01, u23);
                } else {
                    float sv[4];
                    #pragma unroll
                    for (int r = 0; r < 4; ++r) {
                        const float v = acc[mt][nt][r];
                        sv[r] = v / (1.f + __expf(-v));
                    }
                    const uint u01 = pkbf(sv[0], sv[1]);
                    const uint u23 = pkbf(sv[2], sv[3]);
                    *(uint2*)(sp + (size_t)gm * DI + gnb - 1024) = make_uint2(u01, u23);
                }
            }
        }
    } else if (MODE == 2) {
        ushort* fp_ = st ? ob1 : ob0;
        #pragma unroll
        for (int nt = 0; nt < NT; ++nt) {
            const int gn = n0 + wn * (NT * 16) + nt * 16 + lrow;
            #pragma unroll
            for (int mt = 0; mt < MT; ++mt) {
                const int gm = m0 + wm * (MT * 16) + mt * 16 + q * 4;
                const uint u01 = pkbf(acc[mt][nt][0], acc[mt][nt][1]);
                const uint u23 = pkbf(acc[mt][nt][2], acc[mt][nt][3]);
                ushort* bp = fp_ + (size_t)gm * OS + gn;
                bp[0]      = (ushort)u01;
                bp[OS]     = (ushort)(u01 >> 16);
                bp[2 * OS] = (ushort)u23;
                bp[3 * OS] = (ushort)(u23 >> 16);
            }
        }
    } else {  // MODE 3
        const float* xin = st ? x1 : x0;
        float* op = st ? o1 : o0;
        const float g = 1.f / (1.f + __expf(-gate[0]));
        #pragma unroll
        for (int nt = 0; nt < NT; ++nt) {
            const int gn = n0 + wn * (NT * 16) + nt * 16 + lrow;   // channel c
            const float s  = pg[gn] * rsqrtf(pv[gn] + 1e-5f);
            const float sh = pb[gn] - pm[gn] * s;
            #pragma unroll
            for (int mt = 0; mt < MT; ++mt) {
                const int gmb = m0 + wm * (MT * 16) + mt * 16 + q * 4;
                const int b = gmb >> 10, l = gmb & 1023;
                const size_t off = ((size_t)(b * CH + gn)) * L_SZ + l;
                f4 xi = *(const f4*)(xin + off);
                f4 o;
                o.x = xi.x + g * fmaf(acc[mt][nt][0], s, sh);
                o.y = xi.y + g * fmaf(acc[mt][nt][1], s, sh);
                o.z = xi.z + g * fmaf(acc[mt][nt][2], s, sh);
                o.w = xi.w + g * fmaf(acc[mt][nt][3], s, sh);
                *(f4*)(op + off) = o;
            }
        }
    }
}

// ------------------------------------------------------------------
// fused LN + cast  AND  lam MLP (blocks >= 1024) in one dispatch.
// ------------------------------------------------------------------
__global__ __launch_bounds__(256) void k_lnlam(
    const ushort* __restrict__ seq0, const ushort* __restrict__ seq1,
    const float* __restrict__ g0, const float* __restrict__ b0,
    const float* __restrict__ g1, const float* __restrict__ b1,
    ushort* __restrict__ ln0, ushort* __restrict__ ln1,
    const float* __restrict__ p, const float* __restrict__ w1,
    const float* __restrict__ lb1, const float* __restrict__ w2,
    const float* __restrict__ lb2, float* __restrict__ h1,
    float* __restrict__ lamo, unsigned int* __restrict__ cnt)
{
    const int t = threadIdx.x, lane = t & 63, wv = t >> 6;
    if (blockIdx.x >= 1024) {
        __shared__ float lsm[8];
        __shared__ unsigned int tick;
        const int lbk = (blockIdx.x - 1024) * 2 + blockIdx.y;   // 0..127
        const int idx = lbk * 4 + wv;    // 0..511
        const int b = idx >> 7, j = idx & 127;
        const float* pb = p + b * 1024;
        const float* wr = w1 + j * 1024;
        float s = 0.f;
        #pragma unroll
        for (int k = 0; k < 16; ++k)
            s = fmaf(pb[lane + k * 64], wr[lane + k * 64], s);
        #pragma unroll
        for (int off = 1; off < 64; off <<= 1) s += __shfl_xor(s, off, 64);
        if (lane == 0) h1[idx] = fmaxf(s + lb1[j], 0.f);
        __threadfence();
        __syncthreads();
        if (t == 0) tick = atomicAdd(cnt, 1u);
        __syncthreads();
        if (tick != 127u) return;
        __threadfence();
        {
            const int g32 = t >> 5, l32 = t & 31;
            const int bb = g32 >> 1, kk = g32 & 1;
            const float* hb = h1 + bb * 128;
            const float* wr2 = w2 + kk * 128;
            float ss = 0.f;
            #pragma unroll
            for (int u = 0; u < 4; ++u)
                ss = fmaf(hb[l32 + u * 32], wr2[l32 + u * 32], ss);
            #pragma unroll
            for (int off = 1; off < 32; off <<= 1) ss += __shfl_xor(ss, off, 64);
            if (l32 == 0) lsm[g32] = ss + lb2[kk];
        }
        __syncthreads();
        if (t < 4) {
            const float a0 = lsm[t * 2], a1 = lsm[t * 2 + 1];
            const float m  = fmaxf(a0, a1);
            const float e0 = __expf(a0 - m), e1 = __expf(a1 - m);
            const float inv = 1.f / (e0 + e1);
            lamo[t * 2 + 0] = e0 * inv;
            lamo[t * 2 + 1] = e1 * inv;
        }
        return;
    }
    const int row = blockIdx.x * 4 + wv, st = blockIdx.y;
    const ushort* seq = st ? seq1 : seq0;
    const float* gg  = st ? g1 : g0;
    const float* bb  = st ? b1 : b0;
    ushort* ln = st ? ln1 : ln0;
    const u16x8 v = *(const u16x8*)(seq + (size_t)row * DM + lane * 8);
    float f[8];
    float s = 0.f, ss = 0.f;
    #pragma unroll
    for (int i = 0; i < 8; ++i) {
        f[i] = bf2f(v[i]);
        s += f[i];
        ss = fmaf(f[i], f[i], ss);
    }
    #pragma unroll
    for (int off = 1; off < 64; off <<= 1) {
        s += __shfl_xor(s, off, 64); ss += __shfl_xor(ss, off, 64);
    }
    const float mu = s * (1.f / 512.f);
    const float rstd = rsqrtf(ss * (1.f / 512.f) - mu * mu + 1e-5f);
    const f4 gv0 = *(const f4*)(gg + lane * 8);
    const f4 gv1 = *(const f4*)(gg + lane * 8 + 4);
    const f4 bv0 = *(const f4*)(bb + lane * 8);
    const f4 bv1 = *(const f4*)(bb + lane * 8 + 4);
    const float gvv[8] = {gv0.x, gv0.y, gv0.z, gv0.w, gv1.x, gv1.y, gv1.z, gv1.w};
    const float bvv[8] = {bv0.x, bv0.y, bv0.z, bv0.w, bv1.x, bv1.y, bv1.z, bv1.w};
    u16x8 o;
    #pragma unroll
    for (int i = 0; i < 8; i += 2) {
        const uint u = pkbf(fmaf((f[i]     - mu) * rstd, gvv[i],     bvv[i]),
                            fmaf((f[i + 1] - mu) * rstd, gvv[i + 1], bvv[i + 1]));
        o[i]     = (ushort)u;
        o[i + 1] = (ushort)(u >> 16);
    }
    *(u16x8*)(ln + (size_t)row * DM + lane * 8) = o;
}

// ------------------------------------------------------------------
// SSM scan v14 (reverted best): barrier-free compute.
//  - 128-row output chunks (j=0..7), warmup 64.
//  - whole working set (256 rows x 64 ch = 32 KB) staged via 16
//    global_load_lds upfront; ONE barrier; zero syncs during compute.
//  - LDS dest includes srow (wave-correct readfirstlane base).
//  - direction-split lanes: even lane = fwd (all 16 states), odd =
//    bwd. Two independent 8-fma chains per row (ILP).
//  - stash = 32 NAMED uints (bf16 pairs); fwd/bwd exchange via one
//    shfl_xor per 2 rows.
// v15 prefetch: null. v16 wave-split: -87% (shfl on row critical
// path + halved per-thread ILP). v14 = measured plateau.
// ------------------------------------------------------------------
__global__ __launch_bounds__(128, 2) void k_scan(
    const ushort* __restrict__ xsV, const ushort* __restrict__ xsI,
    const ushort* __restrict__ sgV, const ushort* __restrict__ sgI,
    const float* __restrict__ VA, const float* __restrict__ VB,
    const float* __restrict__ VC, const float* __restrict__ IA,
    const float* __restrict__ IB, const float* __restrict__ IC,
    const float* __restrict__ lam,
    ushort* __restrict__ yV, ushort* __restrict__ yI)
{
    __shared__ __align__(16) ushort xt[256][64];     // 32 KB
    const int t = threadIdx.x;
    const int dir = t & 1;                  // 0 = fwd, 1 = bwd
    const int il = t >> 1;                  // 0..63 channel within block
    const int b = blockIdx.y;
    const int st = blockIdx.z >> 3, j = blockIdx.z & 7;
    const int c0 = blockIdx.x * 64;
    const ushort* xrow  = (st ? xsI : xsV) + (size_t)b * L_SZ * DI + c0;
    const ushort* sgrow = (st ? sgI : sgV) + (size_t)b * L_SZ * DI + c0;
    ushort* yrow        = (st ? yI  : yV ) + (size_t)b * L_SZ * DI + c0;
    const float* Alog = st ? IA : VA;
    const float* Cm   = st ? IC : VC;
    const float* Bown = st ? IB : VB;
    const float* Both = st ? VB : IB;
    const float lam0 = lam[b * 2 + 0], lam1 = lam[b * 2 + 1];
    const int row0 = j << 7;                // 128-row chunk
    const int srow = t >> 3;                // 0..15
    const int scol = (t & 7) << 3;          // 16 B per lane
    #pragma unroll
    for (int i = 0; i < 16; ++i) {
        int r = row0 - 64 + i * 16 + srow;
        r = max(0, min(1023, r));
        GLOAD16(xrow + (size_t)r * DI + scol, &xt[i * 16 + srow][0]);
    }
    // per-lane params: all 16 states of ONE direction
    float a[16], w[16], g[16];
    {
        const int cb = (c0 + il) * NS;
        #pragma unroll
        for (int s4 = 0; s4 < 4; ++s4) {
            const f4 av = *(const f4*)(Alog + cb + s4 * 4);
            const f4 cv = *(const f4*)(Cm   + cb + s4 * 4);
            const f4 bo = *(const f4*)(Bown + cb + s4 * 4);
            const f4 bt = *(const f4*)(Both + cb + s4 * 4);
            const float avv[4] = {av.x, av.y, av.z, av.w};
            const float cvv[4] = {cv.x, cv.y, cv.z, cv.w};
            const float bov[4] = {bo.x, bo.y, bo.z, bo.w};
            const float btv[4] = {bt.x, bt.y, bt.z, bt.w};
            #pragma unroll
            for (int q = 0; q < 4; ++q) {
                const int s = s4 * 4 + q;
                a[s] = fminf(fmaxf(-__expf(avv[q]), -10.f), -0.01f);
                w[s] = 0.5f * cvv[q] * fmaf(lam0, bov[q], lam1 * btv[q]);
                g[s] = 0.f;
            }
        }
    }
    __syncthreads();                        // the ONLY barrier

    const ushort* xtf = &xt[0][0];
    int toff = (dir ? 255 : 0) * 64 + il;   // ushort index
    const int tstep = dir ? -64 : 64;

    // warmup: 64 rows (fwd tile 0..63 / bwd tile 255..192)
    #pragma unroll
    for (int n = 0; n < 64; ++n) {
        const float v = bf2f(xtf[toff]); toff += tstep;
        #pragma unroll
        for (int s = 0; s < 16; ++s) g[s] = fmaf(a[s], g[s], v);
    }
    if ((j == 0 && dir == 0) || (j == 7 && dir == 1)) {
        #pragma unroll
        for (int s = 0; s < 16; ++s) g[s] = 0.f;
    }

// one output row: state update + (8+8)-tree reduction
#define SROW(Y) { \
    const float v_ = bf2f(xtf[toff]); toff += tstep; \
    float ye_ = 0.f, yo_ = 0.f; \
    _Pragma("unroll") \
    for (int s = 0; s < 8; ++s) { \
        g[s]     = fmaf(a[s],     g[s],     v_); ye_ = fmaf(g[s],     w[s],     ye_); \
        g[s + 8] = fmaf(a[s + 8], g[s + 8], v_); yo_ = fmaf(g[s + 8], w[s + 8], yo_); \
    } \
    Y = ye_ + yo_; }

// stash two rows into one packed word (fwd rows 2k,2k+1 / bwd 127-2k,126-2k)
#define SPAIR(WREG) { \
    float y0_, y1_; SROW(y0_) SROW(y1_) \
    WREG = (uint)f2bf(y0_) | ((uint)f2bf(y1_) << 16); }

// final two rows: exchange stash with partner lane, combine, store
#define FPAIR(K, WREG) { \
    const uint p_ = __shfl_xor(WREG, 1, 64); \
    float y0_, y1_; \
    SROW(y0_) \
    { const int r_ = row0 + (dir ? (63 - 2 * (K)) : (64 + 2 * (K))); \
      const float z_ = (y0_ + bf2f((ushort)(p_ >> 16))) \
                     * bf2f(sgrow[(size_t)r_ * DI + il]); \
      yrow[(size_t)r_ * DI + il] = f2bf(z_); } \
    SROW(y1_) \
    { const int r_ = row0 + (dir ? (62 - 2 * (K)) : (65 + 2 * (K))); \
      const float z_ = (y1_ + bf2f((ushort)(p_ & 0xFFFFu))) \
                     * bf2f(sgrow[(size_t)r_ * DI + il]); \
      yrow[(size_t)r_ * DI + il] = f2bf(z_); } }

    uint s00, s01, s02, s03, s04, s05, s06, s07;
    uint s08, s09, s10, s11, s12, s13, s14, s15;
    uint s16, s17, s18, s19, s20, s21, s22, s23;
    uint s24, s25, s26, s27, s28, s29, s30, s31;

    // first 64 output rows -> stash
    SPAIR(s00) SPAIR(s01) SPAIR(s02) SPAIR(s03)
    SPAIR(s04) SPAIR(s05) SPAIR(s06) SPAIR(s07)
    SPAIR(s08) SPAIR(s09) SPAIR(s10) SPAIR(s11)
    SPAIR(s12) SPAIR(s13) SPAIR(s14) SPAIR(s15)
    SPAIR(s16) SPAIR(s17) SPAIR(s18) SPAIR(s19)
    SPAIR(s20) SPAIR(s21) SPAIR(s22) SPAIR(s23)
    SPAIR(s24) SPAIR(s25) SPAIR(s26) SPAIR(s27)
    SPAIR(s28) SPAIR(s29) SPAIR(s30) SPAIR(s31)
    // last 64 output rows -> combine with partner stash (reverse order)
    FPAIR(0,  s31) FPAIR(1,  s30) FPAIR(2,  s29) FPAIR(3,  s28)
    FPAIR(4,  s27) FPAIR(5,  s26) FPAIR(6,  s25) FPAIR(7,  s24)
    FPAIR(8,  s23) FPAIR(9,  s22) FPAIR(10, s21) FPAIR(11, s20)
    FPAIR(12, s19) FPAIR(13, s18) FPAIR(14, s17) FPAIR(15, s16)
    FPAIR(16, s15) FPAIR(17, s14) FPAIR(18, s13) FPAIR(19, s12)
    FPAIR(20, s11) FPAIR(21, s10) FPAIR(22, s09) FPAIR(23, s08)
    FPAIR(24, s07) FPAIR(25, s06) FPAIR(26, s05) FPAIR(27, s04)
    FPAIR(28, s03) FPAIR(29, s02) FPAIR(30, s01) FPAIR(31, s00)

#undef SROW
#undef SPAIR
#undef FPAIR
}

// ------------------------------------------------------------------
extern "C" void kernel_launch(void* const* d_in, const int* in_sizes, int n_in,
                              void* d_out, int out_size, void* d_ws, size_t ws_size,
                              hipStream_t stream)
{
    const float* xV       = (const float*)d_in[0];
    const float* xI       = (const float*)d_in[1];
    const float* convredw = (const float*)d_in[2];
    const float* bnredg   = (const float*)d_in[3];
    const float* bnredb   = (const float*)d_in[4];
    const float* bnredm   = (const float*)d_in[5];
    const float* bnredv   = (const float*)d_in[6];
    const float* convresw = (const float*)d_in[7];
    const float* bnresg   = (const float*)d_in[8];
    const float* bnresb   = (const float*)d_in[9];
    const float* bnresm   = (const float*)d_in[10];
    const float* bnresv   = (const float*)d_in[11];
    const float* lamw1    = (const float*)d_in[12];
    const float* lamb1    = (const float*)d_in[13];
    const float* lamw2    = (const float*)d_in[14];
    const float* lamb2    = (const float*)d_in[15];
    const float* Vinw     = (const float*)d_in[16];
    const float* Voutw    = (const float*)d_in[17];
    const float* VAlog    = (const float*)d_in[18];
    const float* VB       = (const float*)d_in[19];
    const float* VC       = (const float*)d_in[20];
    const float* Vlng     = (const float*)d_in[21];
    const float* Vlnb     = (const float*)d_in[22];
    const float* Iinw     = (const float*)d_in[23];
    const float* Ioutw    = (const float*)d_in[24];
    const float* IAlog    = (const float*)d_in[25];
    const float* IB       = (const float*)d_in[26];
    const float* IC       = (const float*)d_in[27];
    const float* Ilng     = (const float*)d_in[28];
    const float* Ilnb     = (const float*)d_in[29];
    const float* gate     = (const float*)d_in[30];

    char* W = (char*)d_ws;
    const size_t MB = 1048576;
    ushort* seqV  = (ushort*)(W + 0);            // 4 MB bf16 (4096,512)
    ushort* seqI  = (ushort*)(W + 4  * MB);      // 4 MB
    float*  p     = (float*)(W + 8 * MB);        // 16 KB
    float*  lam   = (float*)(W + 8 * MB + 16384);
    float*  h1    = (float*)(W + 8 * MB + 32768);
    unsigned int* cnt = (unsigned int*)(W + 8 * MB + 49152);
    ushort* sgV   = (ushort*)(W + 17 * MB);      // 8 MB bf16 (4096,1024)
    ushort* sgI   = (ushort*)(W + 25 * MB);
    ushort* yV    = (ushort*)(W + 33 * MB);      // 8 MB bf16 (4096,1024)
    ushort* yI    = (ushort*)(W + 41 * MB);
    ushort* wred  = (ushort*)(W + 65 * MB);      // 256 KB
    ushort* wres  = (ushort*)(W + 65 * MB + 262144);
    ushort* winV  = (ushort*)(W + 66 * MB);      // 2 MB
    ushort* winI  = (ushort*)(W + 68 * MB);
    ushort* woTv  = (ushort*)(W + 70 * MB);      // 1 MB bf16 (1024,512) = Voutw^T
    ushort* woTi  = (ushort*)(W + 71 * MB);
    ushort* xtV   = (ushort*)(W + 72 * MB);      // 2 MB
    ushort* xtI   = (ushort*)(W + 74 * MB);
    ushort* lnV   = (ushort*)(W + 76 * MB);      // 4 MB
    ushort* lnI   = (ushort*)(W + 80 * MB);
    ushort* xsV   = (ushort*)(W + 84 * MB);      // 8 MB bf16 (4096,1024)
    ushort* xsI   = (ushort*)(W + 92 * MB);
    ushort* wcombV = (ushort*)(W + 100 * MB);    // 512 KB bf16 (256,1024)
    ushort* wcombI = (ushort*)(W + 100 * MB + 524288);   // top = 101 MB
    float*  outp  = (float*)d_out;

    // prep: weight casts + wout transposes + x transpose + zero p/cnt
    k_prep<<<dim3(5377), 256, 0, stream>>>(
        convredw, convresw, Vinw, Iinw, Voutw, Ioutw,
        wred, wres, winV, winI, woTv, woTi,
        xV, xI, xtV, xtI, p, cnt);
    // wcomb[c,k] = sum_d wres[c,d]*wout[d,k]  (256x1024, K=512, bf16 out)
    k_gemm<2, 64, 64, 1024><<<dim3(16, 4, 2), 256, 0, stream>>>(
        wres, wres, woTv, woTi, 512,
        nullptr, nullptr, wcombV, wcombI, nullptr, nullptr,
        nullptr, nullptr, nullptr, nullptr, nullptr, nullptr, nullptr, nullptr);
    // conv_red (MFMA, 128x64) -> seq bf16 + fused pool
    k_gemm<0, 128, 64, 512><<<dim3(8, 32, 2), 256, 0, stream>>>(xtV, xtI, wred, wred, 256,
        nullptr, nullptr, seqV, seqI, nullptr, nullptr,
        bnredg, bnredb, bnredm, bnredv, nullptr, nullptr, nullptr, p);
    // LN -> bf16  +  lambda MLP (fused, one dispatch)
    k_lnlam<<<dim3(1088, 2), 256, 0, stream>>>(
        seqV, seqI, Vlng, Vlnb, Ilng, Ilnb, lnV, lnI,
        p, lamw1, lamb1, lamw2, lamb2, h1, lam, cnt);
    // in_proj (MFMA, 128x128) -> xs bf16, sg bf16
    k_gemm<1, 128, 128, 512><<<dim3(16, 32, 2), 256, 0, stream>>>(lnV, lnI, winV, winI, 512,
        nullptr, nullptr, xsV, xsI, sgV, sgI,
        nullptr, nullptr, nullptr, nullptr, nullptr, nullptr, nullptr, nullptr);
    // fused bidirectional scan v14 -> y bf16 (128-row chunks, j=0..7)
    k_scan<<<dim3(16, 4, 16), 128, 0, stream>>>(xsV, xsI, sgV, sgI,
        VAlog, VB, VC, IAlog, IB, IC, lam, yV, yI);
    // fused out-proj+conv_res (MFMA, 64x64, K=1024, B=wcomb) + residual -> d_out
    k_gemm<3, 64, 64, 512><<<dim3(4, 64, 2), 256, 0, stream>>>(yV, yI, wcombV, wcombI, 1024,
        outp, outp + 1048576, nullptr, nullptr, nullptr, nullptr,
        bnresg, bnresb, bnresm, bnresv, xV, xI, gate, nullptr);
}

// Round 11
// 230.450 us; speedup vs baseline: 1.1811x; 1.0128x over previous
//
#include <hip/hip_runtime.h>
#include <hip/hip_bf16.h>
#include <math.h>

#define L_SZ 1024
#define DM   512
#define DI   1024
#define NS   16
#define CH   256

typedef float4 f4;
typedef __attribute__((ext_vector_type(8))) short short8;
typedef __attribute__((ext_vector_type(8))) unsigned short u16x8;
typedef __attribute__((ext_vector_type(4))) float f32x4;

__device__ __forceinline__ float bf2f(ushort u) {
    union { unsigned int i; float f; } x; x.i = ((unsigned int)u) << 16; return x.f;
}
__device__ __forceinline__ ushort f2bf(float f) {
    union { float f; unsigned int i; } x; x.f = f;
    unsigned int r = x.i + 0x7FFFu + ((x.i >> 16) & 1u);
    return (ushort)(r >> 16);
}
// packed RNE f32x2 -> bf16x2 (v_cvt_pk_bf16_f32 on gfx950)
__device__ __forceinline__ uint pkbf(float a, float b) {
    union { __hip_bfloat162 h; uint u; } c;
    c.h = __float22bfloat162_rn(make_float2(a, b));
    return c.u;
}

#define GLOAD16(gp, lp) \
  __builtin_amdgcn_global_load_lds((const __attribute__((address_space(1))) void*)(gp), \
                                   (__attribute__((address_space(3))) void*)(lp), 16, 0, 0)

template<int N> __device__ __forceinline__ void vmcnt_n() {
    if constexpr (N == 0)      asm volatile("s_waitcnt vmcnt(0)" ::: "memory");
    else if constexpr (N == 2) asm volatile("s_waitcnt vmcnt(2)" ::: "memory");
    else if constexpr (N == 3) asm volatile("s_waitcnt vmcnt(3)" ::: "memory");
    else if constexpr (N == 4) asm volatile("s_waitcnt vmcnt(4)" ::: "memory");
    else if constexpr (N == 6) asm volatile("s_waitcnt vmcnt(6)" ::: "memory");
    else                       asm volatile("s_waitcnt vmcnt(8)" ::: "memory");
}

// ------------------------------------------------------------------
// k_prep: ONE dispatch for all setup work. (unchanged)
// ------------------------------------------------------------------
__global__ __launch_bounds__(256) void k_prep(
    const float* __restrict__ s0, const float* __restrict__ s1,
    const float* __restrict__ s2, const float* __restrict__ s3,
    const float* __restrict__ s4, const float* __restrict__ s5,
    ushort* __restrict__ d0, ushort* __restrict__ d1,
    ushort* __restrict__ d2, ushort* __restrict__ d3,
    ushort* __restrict__ d4, ushort* __restrict__ d5,
    const float* __restrict__ xv, const float* __restrict__ xi,
    ushort* __restrict__ xtv, ushort* __restrict__ xti,
    float* __restrict__ p, unsigned int* __restrict__ cnt)
{
    __shared__ float tile[32][36];
    const int bid = blockIdx.x;
    const int t = threadIdx.x;
    if (bid < 2304) {
        const float* s; ushort* d; int rel;
        if      (bid < 128)  { s = s0; d = d0; rel = bid; }
        else if (bid < 256)  { s = s1; d = d1; rel = bid - 128; }
        else if (bid < 1280) { s = s2; d = d2; rel = bid - 256; }
        else                 { s = s3; d = d3; rel = bid - 1280; }
        const int i = rel * 256 + t;
        f4 v = ((const f4*)s)[i];
        ushort4 o;
        o.x = f2bf(v.x); o.y = f2bf(v.y); o.z = f2bf(v.z); o.w = f2bf(v.w);
        ((ushort4*)d)[i] = o;
        return;
    }
    if (bid < 3328) {
        const int rel = (bid < 2816) ? bid - 2304 : bid - 2816;
        const float* wo = (bid < 2816) ? s4 : s5;
        ushort* wt      = (bid < 2816) ? d4 : d5;
        const int kt = rel & 31, dt = rel >> 5;
        const int d0_ = dt * 32, k0 = kt * 32;
        {
            int cc = t >> 3, ll4 = (t & 7) << 2;
            f4 v = *(const f4*)(wo + (size_t)(d0_ + cc) * 1024 + k0 + ll4);
            tile[cc][ll4 + 0] = v.x; tile[cc][ll4 + 1] = v.y;
            tile[cc][ll4 + 2] = v.z; tile[cc][ll4 + 3] = v.w;
        }
        __syncthreads();
        {
            int ll = t >> 3, cc4 = (t & 7) << 2;
            ushort4 o;
            o.x = f2bf(tile[cc4 + 0][ll]); o.y = f2bf(tile[cc4 + 1][ll]);
            o.z = f2bf(tile[cc4 + 2][ll]); o.w = f2bf(tile[cc4 + 3][ll]);
            *(ushort4*)(wt + (size_t)(k0 + ll) * 512 + d0_ + cc4) = o;
        }
        return;
    }
    if (bid < 5376) {
        const int rel = bid - 3328;
        const int l0 = (rel & 31) * 32, c0 = ((rel >> 5) & 7) * 32;
        const int z = rel >> 8;
        const int b = z & 3, st = z >> 2;
        const float* x = st ? xi : xv;
        ushort* xt = st ? xti : xtv;
        {
            int cc = t >> 3, ll4 = (t & 7) << 2;
            f4 v = *(const f4*)(x + ((size_t)(b * CH + c0 + cc)) * L_SZ + l0 + ll4);
            tile[cc][ll4 + 0] = v.x; tile[cc][ll4 + 1] = v.y;
            tile[cc][ll4 + 2] = v.z; tile[cc][ll4 + 3] = v.w;
        }
        __syncthreads();
        {
            int ll = t >> 3, cc4 = (t & 7) << 2;
            ushort4 o;
            o.x = f2bf(tile[cc4 + 0][ll]); o.y = f2bf(tile[cc4 + 1][ll]);
            o.z = f2bf(tile[cc4 + 2][ll]); o.w = f2bf(tile[cc4 + 3][ll]);
            *(ushort4*)(xt + ((size_t)(b * L_SZ + l0 + ll)) * CH + c0 + cc4) = o;
        }
        return;
    }
    const f4 z4 = {0.f, 0.f, 0.f, 0.f};
    ((f4*)p)[t]       = z4;
    ((f4*)p)[t + 256] = z4;
    ((f4*)p)[t + 512] = z4;
    ((f4*)p)[t + 768] = z4;
    if (t == 0) *cnt = 0u;
}

// ------------------------------------------------------------------
// unified bf16 MFMA GEMM, tiled BM x BN (4 waves 2x2).
// v3: DEPTH-deep LDS pipeline (3 for small-tile modes 0/2/3, 2 for
// mode 1 to preserve 4-blocks/CU residency at 32 KB LDS). Counted
// vmcnt((DEPTH-1)*SPW): the awaited chunk was issued DEPTH-1 compute
// phases ago -> load latency covered. Raw s_barrier, never vmcnt(0)
// mid-loop. Arithmetic unchanged.
// ------------------------------------------------------------------
template<int MODE, int BM, int BN, int OS>
__global__ __launch_bounds__(256) void k_gemm(
    const ushort* __restrict__ A0, const ushort* __restrict__ A1,
    const ushort* __restrict__ B0, const ushort* __restrict__ B1,
    int K,
    float* __restrict__ o0, float* __restrict__ o1,
    ushort* __restrict__ ob0, ushort* __restrict__ ob1,
    ushort* __restrict__ sb0, ushort* __restrict__ sb1,
    const float* __restrict__ pg, const float* __restrict__ pb,
    const float* __restrict__ pm, const float* __restrict__ pv,
    const float* __restrict__ x0, const float* __restrict__ x1,
    const float* __restrict__ gate, float* __restrict__ pp)
{
    constexpr int MT    = BM / 32;
    constexpr int NT    = BN / 32;
    constexpr int ASEG  = BM / 16;
    constexpr int NSEG  = (BM + BN) / 16;
    constexpr int SPW   = NSEG / 4;
    constexpr int DEPTH = (MODE == 1) ? 2 : 3;
    __shared__ __align__(16) ushort Sl[DEPTH][(BM + BN) * 32];
    const int t = threadIdx.x;
    const int wv = t >> 6, lane = t & 63;
    const int n0 = blockIdx.x * BN, m0 = blockIdx.y * BM;
    const int st = blockIdx.z;
    const ushort* Ap = st ? A1 : A0;
    const ushort* Bp = st ? B1 : B0;
    const int wm = wv >> 1, wn = wv & 1;
    const int lrow = lane & 15, q = lane >> 4;
    f32x4 acc[MT][NT];
    #pragma unroll
    for (int a_ = 0; a_ < MT; ++a_)
        #pragma unroll
        for (int b_ = 0; b_ < NT; ++b_)
            acc[a_][b_] = (f32x4){0.f, 0.f, 0.f, 0.f};
    const int srow = lane >> 2;
    const int skk  = (((lane & 3) ^ ((lane >> 3) & 3)) << 3);
    const int koff = ((q ^ ((lrow >> 1) & 3)) << 3);

#define STAGEC(KOFF, BUF) do { \
    _Pragma("unroll") \
    for (int s2 = 0; s2 < SPW; ++s2) { \
        const int seg = wv * SPW + s2; \
        const int grow = (seg < ASEG) ? (m0 + seg * 16 + srow) \
                                      : (n0 + (seg - ASEG) * 16 + srow); \
        const ushort* src = (seg < ASEG) ? Ap : Bp; \
        GLOAD16(src + (size_t)grow * K + (KOFF) + skk, &Sl[BUF][seg * 512]); \
    } \
} while (0)

    // prologue: stage chunk 0 (and chunk 1 for 3-deep)
    STAGEC(0, 0);
    if constexpr (DEPTH == 3) {
        if (32 < K) STAGEC(32, 1);
    }
    int cur = 0;
    for (int k0 = 0; k0 < K; k0 += 32) {
        const int kpre = k0 + (DEPTH - 1) * 32;
        if (kpre < K) {
            int nb = cur + (DEPTH - 1); if (nb >= DEPTH) nb -= DEPTH;
            STAGEC(kpre, nb);
            vmcnt_n<(DEPTH - 1) * SPW>();
        } else if (k0 + 32 < K) {
            vmcnt_n<SPW>();        // only the final chunk still in flight
        } else {
            vmcnt_n<0>();
        }
        __builtin_amdgcn_s_barrier();
        short8 af[MT], bfr[NT];
        #pragma unroll
        for (int mt = 0; mt < MT; ++mt)
            af[mt] = *(const short8*)&Sl[cur][(wm * (MT * 16) + mt * 16 + lrow) * 32 + koff];
        #pragma unroll
        for (int nt = 0; nt < NT; ++nt)
            bfr[nt] = *(const short8*)&Sl[cur][(BM + wn * (NT * 16) + nt * 16 + lrow) * 32 + koff];
        #pragma unroll
        for (int mt = 0; mt < MT; ++mt)
            #pragma unroll
            for (int nt = 0; nt < NT; ++nt) {
                if constexpr (MODE == 1)
                    acc[mt][nt] = __builtin_amdgcn_mfma_f32_16x16x32_bf16(bfr[nt], af[mt], acc[mt][nt], 0, 0, 0);
                else
                    acc[mt][nt] = __builtin_amdgcn_mfma_f32_16x16x32_bf16(af[mt], bfr[nt], acc[mt][nt], 0, 0, 0);
            }
        asm volatile("s_waitcnt lgkmcnt(0)" ::: "memory");
        __builtin_amdgcn_sched_barrier(0);
        __builtin_amdgcn_s_barrier();
        cur = (cur + 1 == DEPTH) ? 0 : cur + 1;
    }
#undef STAGEC
    // epilogue; D layout: row = q*4 + r, col = lrow [m89-verified]
    if (MODE == 0) {
        ushort* sq = st ? ob1 : ob0;
        const int b = m0 >> 10;
        #pragma unroll
        for (int nt = 0; nt < NT; ++nt) {
            const int gn = n0 + wn * (NT * 16) + nt * 16 + lrow;
            const float s  = pg[gn] * rsqrtf(pv[gn] + 1e-5f);
            const float sh = pb[gn] - pm[gn] * s;
            float psum = 0.f;
            #pragma unroll
            for (int mt = 0; mt < MT; ++mt) {
                const int gm = m0 + wm * (MT * 16) + mt * 16 + q * 4;
                float v[4];
                #pragma unroll
                for (int r = 0; r < 4; ++r) {
                    v[r] = fmaxf(fmaf(acc[mt][nt][r], s, sh), 0.f);
                    psum += v[r];
                }
                const uint u01 = pkbf(v[0], v[1]);
                const uint u23 = pkbf(v[2], v[3]);
                ushort* bp = sq + (size_t)gm * DM + gn;
                bp[0]      = (ushort)u01;
                bp[DM]     = (ushort)(u01 >> 16);
                bp[2 * DM] = (ushort)u23;
                bp[3 * DM] = (ushort)(u23 >> 16);
            }
            psum += __shfl_xor(psum, 16, 64);
            psum += __shfl_xor(psum, 32, 64);
            if (q == 0)
                atomicAdd(pp + (b * 1024 + st * 512 + gn), psum * (1.0f / 1024.0f));
        }
    } else if (MODE == 1) {
        const bool isx = (n0 < 1024);
        ushort* xp = st ? ob1 : ob0;
        ushort* sp = st ? sb1 : sb0;
        #pragma unroll
        for (int mt = 0; mt < MT; ++mt) {
            const int gm = m0 + wm * (MT * 16) + mt * 16 + lrow;   // seq row
            #pragma unroll
            for (int nt = 0; nt < NT; ++nt) {
                const int gnb = n0 + wn * (NT * 16) + nt * 16 + q * 4;  // channel base
                if (isx) {
                    const uint u01 = pkbf(acc[mt][nt][0], acc[mt][nt][1]);
                    const uint u23 = pkbf(acc[mt][nt][2], acc[mt][nt][3]);
                    *(uint2*)(xp + (size_t)gm * DI + gnb) = make_uint2(u01, u23);
                } else {
                    float sv[4];
                    #pragma unroll
                    for (int r = 0; r < 4; ++r) {
                        const float v = acc[mt][nt][r];
                        sv[r] = v / (1.f + __expf(-v));
                    }
                    const uint u01 = pkbf(sv[0], sv[1]);
                    const uint u23 = pkbf(sv[2], sv[3]);
                    *(uint2*)(sp + (size_t)gm * DI + gnb - 1024) = make_uint2(u01, u23);
                }
            }
        }
    } else if (MODE == 2) {
        ushort* fp_ = st ? ob1 : ob0;
        #pragma unroll
        for (int nt = 0; nt < NT; ++nt) {
            const int gn = n0 + wn * (NT * 16) + nt * 16 + lrow;
            #pragma unroll
            for (int mt = 0; mt < MT; ++mt) {
                const int gm = m0 + wm * (MT * 16) + mt * 16 + q * 4;
                const uint u01 = pkbf(acc[mt][nt][0], acc[mt][nt][1]);
                const uint u23 = pkbf(acc[mt][nt][2], acc[mt][nt][3]);
                ushort* bp = fp_ + (size_t)gm * OS + gn;
                bp[0]      = (ushort)u01;
                bp[OS]     = (ushort)(u01 >> 16);
                bp[2 * OS] = (ushort)u23;
                bp[3 * OS] = (ushort)(u23 >> 16);
            }
        }
    } else {  // MODE 3
        const float* xin = st ? x1 : x0;
        float* op = st ? o1 : o0;
        const float g = 1.f / (1.f + __expf(-gate[0]));
        #pragma unroll
        for (int nt = 0; nt < NT; ++nt) {
            const int gn = n0 + wn * (NT * 16) + nt * 16 + lrow;   // channel c
            const float s  = pg[gn] * rsqrtf(pv[gn] + 1e-5f);
            const float sh = pb[gn] - pm[gn] * s;
            #pragma unroll
            for (int mt = 0; mt < MT; ++mt) {
                const int gmb = m0 + wm * (MT * 16) + mt * 16 + q * 4;
                const int b = gmb >> 10, l = gmb & 1023;
                const size_t off = ((size_t)(b * CH + gn)) * L_SZ + l;
                f4 xi = *(const f4*)(xin + off);
                f4 o;
                o.x = xi.x + g * fmaf(acc[mt][nt][0], s, sh);
                o.y = xi.y + g * fmaf(acc[mt][nt][1], s, sh);
                o.z = xi.z + g * fmaf(acc[mt][nt][2], s, sh);
                o.w = xi.w + g * fmaf(acc[mt][nt][3], s, sh);
                *(f4*)(op + off) = o;
            }
        }
    }
}

// ------------------------------------------------------------------
// fused LN + cast  AND  lam MLP (blocks >= 1024) in one dispatch.
// ------------------------------------------------------------------
__global__ __launch_bounds__(256) void k_lnlam(
    const ushort* __restrict__ seq0, const ushort* __restrict__ seq1,
    const float* __restrict__ g0, const float* __restrict__ b0,
    const float* __restrict__ g1, const float* __restrict__ b1,
    ushort* __restrict__ ln0, ushort* __restrict__ ln1,
    const float* __restrict__ p, const float* __restrict__ w1,
    const float* __restrict__ lb1, const float* __restrict__ w2,
    const float* __restrict__ lb2, float* __restrict__ h1,
    float* __restrict__ lamo, unsigned int* __restrict__ cnt)
{
    const int t = threadIdx.x, lane = t & 63, wv = t >> 6;
    if (blockIdx.x >= 1024) {
        __shared__ float lsm[8];
        __shared__ unsigned int tick;
        const int lbk = (blockIdx.x - 1024) * 2 + blockIdx.y;   // 0..127
        const int idx = lbk * 4 + wv;    // 0..511
        const int b = idx >> 7, j = idx & 127;
        const float* pb = p + b * 1024;
        const float* wr = w1 + j * 1024;
        float s = 0.f;
        #pragma unroll
        for (int k = 0; k < 16; ++k)
            s = fmaf(pb[lane + k * 64], wr[lane + k * 64], s);
        #pragma unroll
        for (int off = 1; off < 64; off <<= 1) s += __shfl_xor(s, off, 64);
        if (lane == 0) h1[idx] = fmaxf(s + lb1[j], 0.f);
        __threadfence();
        __syncthreads();
        if (t == 0) tick = atomicAdd(cnt, 1u);
        __syncthreads();
        if (tick != 127u) return;
        __threadfence();
        {
            const int g32 = t >> 5, l32 = t & 31;
            const int bb = g32 >> 1, kk = g32 & 1;
            const float* hb = h1 + bb * 128;
            const float* wr2 = w2 + kk * 128;
            float ss = 0.f;
            #pragma unroll
            for (int u = 0; u < 4; ++u)
                ss = fmaf(hb[l32 + u * 32], wr2[l32 + u * 32], ss);
            #pragma unroll
            for (int off = 1; off < 32; off <<= 1) ss += __shfl_xor(ss, off, 64);
            if (l32 == 0) lsm[g32] = ss + lb2[kk];
        }
        __syncthreads();
        if (t < 4) {
            const float a0 = lsm[t * 2], a1 = lsm[t * 2 + 1];
            const float m  = fmaxf(a0, a1);
            const float e0 = __expf(a0 - m), e1 = __expf(a1 - m);
            const float inv = 1.f / (e0 + e1);
            lamo[t * 2 + 0] = e0 * inv;
            lamo[t * 2 + 1] = e1 * inv;
        }
        return;
    }
    const int row = blockIdx.x * 4 + wv, st = blockIdx.y;
    const ushort* seq = st ? seq1 : seq0;
    const float* gg  = st ? g1 : g0;
    const float* bb  = st ? b1 : b0;
    ushort* ln = st ? ln1 : ln0;
    const u16x8 v = *(const u16x8*)(seq + (size_t)row * DM + lane * 8);
    float f[8];
    float s = 0.f, ss = 0.f;
    #pragma unroll
    for (int i = 0; i < 8; ++i) {
        f[i] = bf2f(v[i]);
        s += f[i];
        ss = fmaf(f[i], f[i], ss);
    }
    #pragma unroll
    for (int off = 1; off < 64; off <<= 1) {
        s += __shfl_xor(s, off, 64); ss += __shfl_xor(ss, off, 64);
    }
    const float mu = s * (1.f / 512.f);
    const float rstd = rsqrtf(ss * (1.f / 512.f) - mu * mu + 1e-5f);
    const f4 gv0 = *(const f4*)(gg + lane * 8);
    const f4 gv1 = *(const f4*)(gg + lane * 8 + 4);
    const f4 bv0 = *(const f4*)(bb + lane * 8);
    const f4 bv1 = *(const f4*)(bb + lane * 8 + 4);
    const float gvv[8] = {gv0.x, gv0.y, gv0.z, gv0.w, gv1.x, gv1.y, gv1.z, gv1.w};
    const float bvv[8] = {bv0.x, bv0.y, bv0.z, bv0.w, bv1.x, bv1.y, bv1.z, bv1.w};
    u16x8 o;
    #pragma unroll
    for (int i = 0; i < 8; i += 2) {
        const uint u = pkbf(fmaf((f[i]     - mu) * rstd, gvv[i],     bvv[i]),
                            fmaf((f[i + 1] - mu) * rstd, gvv[i + 1], bvv[i + 1]));
        o[i]     = (ushort)u;
        o[i + 1] = (ushort)(u >> 16);
    }
    *(u16x8*)(ln + (size_t)row * DM + lane * 8) = o;
}

// ------------------------------------------------------------------
// SSM scan v14 (plateau best): barrier-free compute. (unchanged)
// ------------------------------------------------------------------
__global__ __launch_bounds__(128, 2) void k_scan(
    const ushort* __restrict__ xsV, const ushort* __restrict__ xsI,
    const ushort* __restrict__ sgV, const ushort* __restrict__ sgI,
    const float* __restrict__ VA, const float* __restrict__ VB,
    const float* __restrict__ VC, const float* __restrict__ IA,
    const float* __restrict__ IB, const float* __restrict__ IC,
    const float* __restrict__ lam,
    ushort* __restrict__ yV, ushort* __restrict__ yI)
{
    __shared__ __align__(16) ushort xt[256][64];     // 32 KB
    const int t = threadIdx.x;
    const int dir = t & 1;                  // 0 = fwd, 1 = bwd
    const int il = t >> 1;                  // 0..63 channel within block
    const int b = blockIdx.y;
    const int st = blockIdx.z >> 3, j = blockIdx.z & 7;
    const int c0 = blockIdx.x * 64;
    const ushort* xrow  = (st ? xsI : xsV) + (size_t)b * L_SZ * DI + c0;
    const ushort* sgrow = (st ? sgI : sgV) + (size_t)b * L_SZ * DI + c0;
    ushort* yrow        = (st ? yI  : yV ) + (size_t)b * L_SZ * DI + c0;
    const float* Alog = st ? IA : VA;
    const float* Cm   = st ? IC : VC;
    const float* Bown = st ? IB : VB;
    const float* Both = st ? VB : IB;
    const float lam0 = lam[b * 2 + 0], lam1 = lam[b * 2 + 1];
    const int row0 = j << 7;                // 128-row chunk
    const int srow = t >> 3;                // 0..15
    const int scol = (t & 7) << 3;          // 16 B per lane
    #pragma unroll
    for (int i = 0; i < 16; ++i) {
        int r = row0 - 64 + i * 16 + srow;
        r = max(0, min(1023, r));
        GLOAD16(xrow + (size_t)r * DI + scol, &xt[i * 16 + srow][0]);
    }
    // per-lane params: all 16 states of ONE direction
    float a[16], w[16], g[16];
    {
        const int cb = (c0 + il) * NS;
        #pragma unroll
        for (int s4 = 0; s4 < 4; ++s4) {
            const f4 av = *(const f4*)(Alog + cb + s4 * 4);
            const f4 cv = *(const f4*)(Cm   + cb + s4 * 4);
            const f4 bo = *(const f4*)(Bown + cb + s4 * 4);
            const f4 bt = *(const f4*)(Both + cb + s4 * 4);
            const float avv[4] = {av.x, av.y, av.z, av.w};
            const float cvv[4] = {cv.x, cv.y, cv.z, cv.w};
            const float bov[4] = {bo.x, bo.y, bo.z, bo.w};
            const float btv[4] = {bt.x, bt.y, bt.z, bt.w};
            #pragma unroll
            for (int q = 0; q < 4; ++q) {
                const int s = s4 * 4 + q;
                a[s] = fminf(fmaxf(-__expf(avv[q]), -10.f), -0.01f);
                w[s] = 0.5f * cvv[q] * fmaf(lam0, bov[q], lam1 * btv[q]);
                g[s] = 0.f;
            }
        }
    }
    __syncthreads();                        // the ONLY barrier

    const ushort* xtf = &xt[0][0];
    int toff = (dir ? 255 : 0) * 64 + il;   // ushort index
    const int tstep = dir ? -64 : 64;

    // warmup: 64 rows (fwd tile 0..63 / bwd tile 255..192)
    #pragma unroll
    for (int n = 0; n < 64; ++n) {
        const float v = bf2f(xtf[toff]); toff += tstep;
        #pragma unroll
        for (int s = 0; s < 16; ++s) g[s] = fmaf(a[s], g[s], v);
    }
    if ((j == 0 && dir == 0) || (j == 7 && dir == 1)) {
        #pragma unroll
        for (int s = 0; s < 16; ++s) g[s] = 0.f;
    }

// one output row: state update + (8+8)-tree reduction
#define SROW(Y) { \
    const float v_ = bf2f(xtf[toff]); toff += tstep; \
    float ye_ = 0.f, yo_ = 0.f; \
    _Pragma("unroll") \
    for (int s = 0; s < 8; ++s) { \
        g[s]     = fmaf(a[s],     g[s],     v_); ye_ = fmaf(g[s],     w[s],     ye_); \
        g[s + 8] = fmaf(a[s + 8], g[s + 8], v_); yo_ = fmaf(g[s + 8], w[s + 8], yo_); \
    } \
    Y = ye_ + yo_; }

// stash two rows into one packed word (fwd rows 2k,2k+1 / bwd 127-2k,126-2k)
#define SPAIR(WREG) { \
    float y0_, y1_; SROW(y0_) SROW(y1_) \
    WREG = (uint)f2bf(y0_) | ((uint)f2bf(y1_) << 16); }

// final two rows: exchange stash with partner lane, combine, store
#define FPAIR(K, WREG) { \
    const uint p_ = __shfl_xor(WREG, 1, 64); \
    float y0_, y1_; \
    SROW(y0_) \
    { const int r_ = row0 + (dir ? (63 - 2 * (K)) : (64 + 2 * (K))); \
      const float z_ = (y0_ + bf2f((ushort)(p_ >> 16))) \
                     * bf2f(sgrow[(size_t)r_ * DI + il]); \
      yrow[(size_t)r_ * DI + il] = f2bf(z_); } \
    SROW(y1_) \
    { const int r_ = row0 + (dir ? (62 - 2 * (K)) : (65 + 2 * (K))); \
      const float z_ = (y1_ + bf2f((ushort)(p_ & 0xFFFFu))) \
                     * bf2f(sgrow[(size_t)r_ * DI + il]); \
      yrow[(size_t)r_ * DI + il] = f2bf(z_); } }

    uint s00, s01, s02, s03, s04, s05, s06, s07;
    uint s08, s09, s10, s11, s12, s13, s14, s15;
    uint s16, s17, s18, s19, s20, s21, s22, s23;
    uint s24, s25, s26, s27, s28, s29, s30, s31;

    // first 64 output rows -> stash
    SPAIR(s00) SPAIR(s01) SPAIR(s02) SPAIR(s03)
    SPAIR(s04) SPAIR(s05) SPAIR(s06) SPAIR(s07)
    SPAIR(s08) SPAIR(s09) SPAIR(s10) SPAIR(s11)
    SPAIR(s12) SPAIR(s13) SPAIR(s14) SPAIR(s15)
    SPAIR(s16) SPAIR(s17) SPAIR(s18) SPAIR(s19)
    SPAIR(s20) SPAIR(s21) SPAIR(s22) SPAIR(s23)
    SPAIR(s24) SPAIR(s25) SPAIR(s26) SPAIR(s27)
    SPAIR(s28) SPAIR(s29) SPAIR(s30) SPAIR(s31)
    // last 64 output rows -> combine with partner stash (reverse order)
    FPAIR(0,  s31) FPAIR(1,  s30) FPAIR(2,  s29) FPAIR(3,  s28)
    FPAIR(4,  s27) FPAIR(5,  s26) FPAIR(6,  s25) FPAIR(7,  s24)
    FPAIR(8,  s23) FPAIR(9,  s22) FPAIR(10, s21) FPAIR(11, s20)
    FPAIR(12, s19) FPAIR(13, s18) FPAIR(14, s17) FPAIR(15, s16)
    FPAIR(16, s15) FPAIR(17, s14) FPAIR(18, s13) FPAIR(19, s12)
    FPAIR(20, s11) FPAIR(21, s10) FPAIR(22, s09) FPAIR(23, s08)
    FPAIR(24, s07) FPAIR(25, s06) FPAIR(26, s05) FPAIR(27, s04)
    FPAIR(28, s03) FPAIR(29, s02) FPAIR(30, s01) FPAIR(31, s00)

#undef SROW
#undef SPAIR
#undef FPAIR
}

// ------------------------------------------------------------------
extern "C" void kernel_launch(void* const* d_in, const int* in_sizes, int n_in,
                              void* d_out, int out_size, void* d_ws, size_t ws_size,
                              hipStream_t stream)
{
    const float* xV       = (const float*)d_in[0];
    const float* xI       = (const float*)d_in[1];
    const float* convredw = (const float*)d_in[2];
    const float* bnredg   = (const float*)d_in[3];
    const float* bnredb   = (const float*)d_in[4];
    const float* bnredm   = (const float*)d_in[5];
    const float* bnredv   = (const float*)d_in[6];
    const float* convresw = (const float*)d_in[7];
    const float* bnresg   = (const float*)d_in[8];
    const float* bnresb   = (const float*)d_in[9];
    const float* bnresm   = (const float*)d_in[10];
    const float* bnresv   = (const float*)d_in[11];
    const float* lamw1    = (const float*)d_in[12];
    const float* lamb1    = (const float*)d_in[13];
    const float* lamw2    = (const float*)d_in[14];
    const float* lamb2    = (const float*)d_in[15];
    const float* Vinw     = (const float*)d_in[16];
    const float* Voutw    = (const float*)d_in[17];
    const float* VAlog    = (const float*)d_in[18];
    const float* VB       = (const float*)d_in[19];
    const float* VC       = (const float*)d_in[20];
    const float* Vlng     = (const float*)d_in[21];
    const float* Vlnb     = (const float*)d_in[22];
    const float* Iinw     = (const float*)d_in[23];
    const float* Ioutw    = (const float*)d_in[24];
    const float* IAlog    = (const float*)d_in[25];
    const float* IB       = (const float*)d_in[26];
    const float* IC       = (const float*)d_in[27];
    const float* Ilng     = (const float*)d_in[28];
    const float* Ilnb     = (const float*)d_in[29];
    const float* gate     = (const float*)d_in[30];

    char* W = (char*)d_ws;
    const size_t MB = 1048576;
    ushort* seqV  = (ushort*)(W + 0);            // 4 MB bf16 (4096,512)
    ushort* seqI  = (ushort*)(W + 4  * MB);      // 4 MB
    float*  p     = (float*)(W + 8 * MB);        // 16 KB
    float*  lam   = (float*)(W + 8 * MB + 16384);
    float*  h1    = (float*)(W + 8 * MB + 32768);
    unsigned int* cnt = (unsigned int*)(W + 8 * MB + 49152);
    ushort* sgV   = (ushort*)(W + 17 * MB);      // 8 MB bf16 (4096,1024)
    ushort* sgI   = (ushort*)(W + 25 * MB);
    ushort* yV    = (ushort*)(W + 33 * MB);      // 8 MB bf16 (4096,1024)
    ushort* yI    = (ushort*)(W + 41 * MB);
    ushort* wred  = (ushort*)(W + 65 * MB);      // 256 KB
    ushort* wres  = (ushort*)(W + 65 * MB + 262144);
    ushort* winV  = (ushort*)(W + 66 * MB);      // 2 MB
    ushort* winI  = (ushort*)(W + 68 * MB);
    ushort* woTv  = (ushort*)(W + 70 * MB);      // 1 MB bf16 (1024,512) = Voutw^T
    ushort* woTi  = (ushort*)(W + 71 * MB);
    ushort* xtV   = (ushort*)(W + 72 * MB);      // 2 MB
    ushort* xtI   = (ushort*)(W + 74 * MB);
    ushort* lnV   = (ushort*)(W + 76 * MB);      // 4 MB
    ushort* lnI   = (ushort*)(W + 80 * MB);
    ushort* xsV   = (ushort*)(W + 84 * MB);      // 8 MB bf16 (4096,1024)
    ushort* xsI   = (ushort*)(W + 92 * MB);
    ushort* wcombV = (ushort*)(W + 100 * MB);    // 512 KB bf16 (256,1024)
    ushort* wcombI = (ushort*)(W + 100 * MB + 524288);   // top = 101 MB
    float*  outp  = (float*)d_out;

    // prep: weight casts + wout transposes + x transpose + zero p/cnt
    k_prep<<<dim3(5377), 256, 0, stream>>>(
        convredw, convresw, Vinw, Iinw, Voutw, Ioutw,
        wred, wres, winV, winI, woTv, woTi,
        xV, xI, xtV, xtI, p, cnt);
    // wcomb[c,k] = sum_d wres[c,d]*wout[d,k]  (256x1024, K=512, bf16 out)
    k_gemm<2, 64, 64, 1024><<<dim3(16, 4, 2), 256, 0, stream>>>(
        wres, wres, woTv, woTi, 512,
        nullptr, nullptr, wcombV, wcombI, nullptr, nullptr,
        nullptr, nullptr, nullptr, nullptr, nullptr, nullptr, nullptr, nullptr);
    // conv_red (MFMA, 128x64) -> seq bf16 + fused pool
    k_gemm<0, 128, 64, 512><<<dim3(8, 32, 2), 256, 0, stream>>>(xtV, xtI, wred, wred, 256,
        nullptr, nullptr, seqV, seqI, nullptr, nullptr,
        bnredg, bnredb, bnredm, bnredv, nullptr, nullptr, nullptr, p);
    // LN -> bf16  +  lambda MLP (fused, one dispatch)
    k_lnlam<<<dim3(1088, 2), 256, 0, stream>>>(
        seqV, seqI, Vlng, Vlnb, Ilng, Ilnb, lnV, lnI,
        p, lamw1, lamb1, lamw2, lamb2, h1, lam, cnt);
    // in_proj (MFMA, 128x128) -> xs bf16, sg bf16
    k_gemm<1, 128, 128, 512><<<dim3(16, 32, 2), 256, 0, stream>>>(lnV, lnI, winV, winI, 512,
        nullptr, nullptr, xsV, xsI, sgV, sgI,
        nullptr, nullptr, nullptr, nullptr, nullptr, nullptr, nullptr, nullptr);
    // fused bidirectional scan v14 -> y bf16 (128-row chunks, j=0..7)
    k_scan<<<dim3(16, 4, 16), 128, 0, stream>>>(xsV, xsI, sgV, sgI,
        VAlog, VB, VC, IAlog, IB, IC, lam, yV, yI);
    // fused out-proj+conv_res (MFMA, 64x64, K=1024, B=wcomb) + residual -> d_out
    k_gemm<3, 64, 64, 512><<<dim3(4, 64, 2), 256, 0, stream>>>(yV, yI, wcombV, wcombI, 1024,
        outp, outp + 1048576, nullptr, nullptr, nullptr, nullptr,
        bnresg, bnresb, bnresm, bnresv, xV, xI, gate, nullptr);
}